// Round 11
// baseline (3035.590 us; speedup 1.0000x reference)
//
#include <hip/hip_runtime.h>
#include <hip/hip_bf16.h>
#include <math.h>

#define B_   32
#define L_   1024
#define CIN_ 64
#define D_   512
#define DFF_ 2048
#define NL_  3
#define TOPK_ 6
#define NBLD_ ((size_t)B_ * L_ * D_)

#define TM 64
#define TN 64
#define TBK 16

typedef unsigned short u16;
typedef __bf16 bf16x8 __attribute__((ext_vector_type(8)));
typedef _Float16 f16x8 __attribute__((ext_vector_type(8)));
typedef float  f32x4  __attribute__((ext_vector_type(4)));

typedef const __attribute__((address_space(1))) void* gp1_t;
typedef __attribute__((address_space(3))) void* lp3_t;

__device__ __forceinline__ void gll16(const void* g, void* l) {
  __builtin_amdgcn_global_load_lds((gp1_t)g, (lp3_t)l, 16, 0, 0);
}

__device__ __forceinline__ float bf2f(u16 u) {
  return __uint_as_float(((unsigned int)u) << 16);
}
__device__ __forceinline__ u16 f2bf(float f) {
  unsigned int u = __float_as_uint(f);
  return (u16)((u + 0x7fffu + ((u >> 16) & 1u)) >> 16);   // RNE
}
__device__ __forceinline__ unsigned int split2(float f) {
  u16 hi = f2bf(f);
  u16 lo = f2bf(f - bf2f(hi));
  return (unsigned int)hi | ((unsigned int)lo << 16);
}
__device__ __forceinline__ u16 f2h(float f) {
  union { _Float16 h; u16 u; } cv;
  cv.h = (_Float16)f;                                      // v_cvt_f16_f32 RNE
  return cv.u;
}
__device__ __forceinline__ float gelu_f(float x) {
  return 0.5f * x * (1.0f + erff(x * 0.70710678118654752440f));
}

__global__ __launch_bounds__(256) void zero_k(float* __restrict__ p, int n) {
  int i = blockIdx.x * 256 + threadIdx.x;
  if (i < n) p[i] = 0.f;
}

// ------- weight transpose (z = layer): bf16x2 split planes, OR (z >= f16_from)
// an fp16 single plane written INTO the hi slot (lo slot untouched/unused).
__global__ __launch_bounds__(256) void transp_split_k(const float* __restrict__ W,
                                                      u16* __restrict__ WTh,
                                                      u16* __restrict__ WTl,
                                                      int K, int N, int stride,
                                                      int f16_from) {
  __shared__ float tile[32][33];
  const int z = blockIdx.z;
  W   += (size_t)z * stride;
  WTh += (size_t)z * stride;
  WTl += (size_t)z * stride;
  const int t = threadIdx.x;
  const int k0 = blockIdx.x * 32, n0 = blockIdx.y * 32;
  const int tx = t & 31, ty = t >> 5;
#pragma unroll
  for (int i = 0; i < 4; ++i) {
    int kk = ty + i * 8;
    tile[kk][tx] = W[(size_t)(k0 + kk) * N + n0 + tx];
  }
  __syncthreads();
#pragma unroll
  for (int i = 0; i < 4; ++i) {
    int nn = ty + i * 8;
    float v = tile[tx][nn];
    size_t o = (size_t)(n0 + nn) * K + k0 + tx;
    if (z >= f16_from) {
      WTh[o] = f2h(v);
    } else {
      unsigned int s = split2(v);
      WTh[o] = (u16)(s & 0xffffu);
      WTl[o] = (u16)(s >> 16);
    }
  }
}

// ============ async split MFMA GEMM with vectorized LDS-bounce epilogue ============
// mode 0: +bias +R(hi/lo) -> fp32 ; 1: gelu -> split ; 2: fp32 += ; 3: +bias -> split
// mode 4: gelu -> fp16 single plane.
// grid.z==2 selects (W2,C2,bias2) for z=1 (merged Q/K launch).
__global__ __launch_bounds__(256) void mfma_split_gemm_k(
    const u16* __restrict__ Ah, const u16* __restrict__ Al, int lda,
    const u16* Wh, const u16* Wl, int ldwt,
    void* Cv, int ldc,
    const float* bias,
    const u16* __restrict__ Rh, const u16* __restrict__ Rl,
    int K, int mode,
    const u16* W2h, const u16* W2l, void* C2v, const float* bias2)
{
  if (blockIdx.z == 1) { Wh = W2h; Wl = W2l; Cv = C2v; bias = bias2; }
  __shared__ __align__(16) char smem[32768];
  u16* Ash = (u16*)smem;
  u16* Asl = Ash + 128 * 32;
  u16* Bsh = Asl + 128 * 32;
  u16* Bsl = Bsh + 128 * 32;
  const int t = threadIdx.x;
  const int m0 = blockIdx.x * 128, n0 = blockIdx.y * 128;
  const int lane = t & 63, w = t >> 6;
  const int lrow = lane >> 2, lq = lane & 3;
  const int qg8 = (lq ^ ((lrow >> 1) & 3)) * 8;
  const int wm = (w & 1) * 64, wn = (w >> 1) * 64;
  const int lm = lane & 15, quad = lane >> 4;
  const int kq8 = (quad ^ ((lm >> 1) & 3)) * 8;

  f32x4 acc[4][4];
#pragma unroll
  for (int i = 0; i < 4; ++i)
#pragma unroll
    for (int j = 0; j < 4; ++j) acc[i][j] = (f32x4){0.f, 0.f, 0.f, 0.f};

  for (int k0 = 0; k0 < K; k0 += 32) {
    __syncthreads();
#pragma unroll
    for (int seg = 0; seg < 2; ++seg) {
      const int r0 = w * 32 + seg * 16;
      const size_t ga = (size_t)(m0 + r0 + lrow) * lda + k0 + qg8;
      const size_t gb = (size_t)(n0 + r0 + lrow) * ldwt + k0 + qg8;
      gll16(Ah + ga, &Ash[r0 * 32]);
      gll16(Al + ga, &Asl[r0 * 32]);
      gll16(Wh + gb, &Bsh[r0 * 32]);
      gll16(Wl + gb, &Bsl[r0 * 32]);
    }
    __syncthreads();

    bf16x8 afh[4], afl[4], bfh[4], bfl[4];
#pragma unroll
    for (int mi = 0; mi < 4; ++mi) {
      afh[mi] = *(const bf16x8*)&Ash[(wm + mi * 16 + lm) * 32 + kq8];
      afl[mi] = *(const bf16x8*)&Asl[(wm + mi * 16 + lm) * 32 + kq8];
    }
#pragma unroll
    for (int ni = 0; ni < 4; ++ni) {
      bfh[ni] = *(const bf16x8*)&Bsh[(wn + ni * 16 + lm) * 32 + kq8];
      bfl[ni] = *(const bf16x8*)&Bsl[(wn + ni * 16 + lm) * 32 + kq8];
    }
#pragma unroll
    for (int mi = 0; mi < 4; ++mi)
#pragma unroll
      for (int ni = 0; ni < 4; ++ni) {
        acc[mi][ni] = __builtin_amdgcn_mfma_f32_16x16x32_bf16(afh[mi], bfh[ni], acc[mi][ni], 0, 0, 0);
        acc[mi][ni] = __builtin_amdgcn_mfma_f32_16x16x32_bf16(afh[mi], bfl[ni], acc[mi][ni], 0, 0, 0);
        acc[mi][ni] = __builtin_amdgcn_mfma_f32_16x16x32_bf16(afl[mi], bfh[ni], acc[mi][ni], 0, 0, 0);
      }
  }

  // -------- vectorized epilogue: per-wave LDS bounce (2 rounds of 32x64) --------
  float bcol[4];
#pragma unroll
  for (int ni = 0; ni < 4; ++ni)
    bcol[ni] = (bias && (mode == 0 || mode == 3)) ? bias[n0 + wn + ni * 16 + lm] : 0.f;
  __syncthreads();                       // all staging reads done before aliasing
  float* epi = (float*)smem + w * 2048;  // 8KB per wave
  float* Cf = (float*)Cv;
  u16* Cu = (u16*)Cv;
#pragma unroll
  for (int mi2 = 0; mi2 < 2; ++mi2) {
#pragma unroll
    for (int mm = 0; mm < 2; ++mm) {
      int mi = mi2 * 2 + mm;
#pragma unroll
      for (int ni = 0; ni < 4; ++ni)
#pragma unroll
        for (int r = 0; r < 4; ++r)
          epi[(mm * 16 + quad * 4 + r) * 64 + ni * 16 + lm] = acc[mi][ni][r] + bcol[ni];
    }
#pragma unroll
    for (int i = 0; i < 8; ++i) {
      int f = lane + 64 * i;
      int row = f >> 4, c4 = f & 15;
      int gr = m0 + wm + mi2 * 32 + row;
      int gc = n0 + wn + c4 * 4;
      size_t ci = (size_t)gr * ldc + gc;
      float4 v = *(const float4*)&epi[row * 64 + c4 * 4];
      if (mode == 0) {
        if (Rh) {
          ushort4 rh = *(const ushort4*)&Rh[ci];
          ushort4 rl = *(const ushort4*)&Rl[ci];
          v.x += bf2f(rh.x) + bf2f(rl.x); v.y += bf2f(rh.y) + bf2f(rl.y);
          v.z += bf2f(rh.z) + bf2f(rl.z); v.w += bf2f(rh.w) + bf2f(rl.w);
        }
        *(float4*)&Cf[ci] = v;
      } else if (mode == 2) {
        float4 o = *(const float4*)&Cf[ci];
        v.x += o.x; v.y += o.y; v.z += o.z; v.w += o.w;
        *(float4*)&Cf[ci] = v;
      } else if (mode == 4) {
        ushort4 hv;
        hv.x = f2h(gelu_f(v.x)); hv.y = f2h(gelu_f(v.y));
        hv.z = f2h(gelu_f(v.z)); hv.w = f2h(gelu_f(v.w));
        *(ushort4*)&Cu[ci] = hv;
      } else {
        if (mode == 1) { v.x = gelu_f(v.x); v.y = gelu_f(v.y); v.z = gelu_f(v.z); v.w = gelu_f(v.w); }
        unsigned int s0 = split2(v.x), s1 = split2(v.y), s2 = split2(v.z), s3 = split2(v.w);
        ushort4 hv, lv;
        hv.x = (u16)s0; hv.y = (u16)s1; hv.z = (u16)s2; hv.w = (u16)s3;
        lv.x = (u16)(s0 >> 16); lv.y = (u16)(s1 >> 16); lv.z = (u16)(s2 >> 16); lv.w = (u16)(s3 >> 16);
        *(ushort4*)&Cu[ci] = hv;
        *(ushort4*)&Cu[ci + NBLD_] = lv;
      }
    }
  }
}

// ============ async plain bf16 MFMA GEMM (hi planes; last-layer V) ============
// mode 0: +bias +R -> fp32 ; mode 2: fp32 += ; mode 4: gelu -> fp16 single.
__global__ __launch_bounds__(256) void mfma_plain_gemm_k(
    const u16* __restrict__ Ah, int lda,
    const u16* __restrict__ Wh, int ldwt,
    void* __restrict__ Cv, int ldc,
    const float* __restrict__ bias,
    const u16* __restrict__ Rh, const u16* __restrict__ Rl,
    int K, int mode)
{
  __shared__ __align__(16) char smem[32768];
  u16* Ash = (u16*)smem;
  u16* Bsh = Ash + 128 * 32;
  const int t = threadIdx.x;
  const int m0 = blockIdx.x * 128, n0 = blockIdx.y * 128;
  const int lane = t & 63, w = t >> 6;
  const int lrow = lane >> 2, lq = lane & 3;
  const int qg8 = (lq ^ ((lrow >> 1) & 3)) * 8;
  const int wm = (w & 1) * 64, wn = (w >> 1) * 64;
  const int lm = lane & 15, quad = lane >> 4;
  const int kq8 = (quad ^ ((lm >> 1) & 3)) * 8;

  f32x4 acc[4][4];
#pragma unroll
  for (int i = 0; i < 4; ++i)
#pragma unroll
    for (int j = 0; j < 4; ++j) acc[i][j] = (f32x4){0.f, 0.f, 0.f, 0.f};

  for (int k0 = 0; k0 < K; k0 += 32) {
    __syncthreads();
#pragma unroll
    for (int seg = 0; seg < 2; ++seg) {
      const int r0 = w * 32 + seg * 16;
      const size_t ga = (size_t)(m0 + r0 + lrow) * lda + k0 + qg8;
      const size_t gb = (size_t)(n0 + r0 + lrow) * ldwt + k0 + qg8;
      gll16(Ah + ga, &Ash[r0 * 32]);
      gll16(Wh + gb, &Bsh[r0 * 32]);
    }
    __syncthreads();

    bf16x8 af[4], bf[4];
#pragma unroll
    for (int mi = 0; mi < 4; ++mi)
      af[mi] = *(const bf16x8*)&Ash[(wm + mi * 16 + lm) * 32 + kq8];
#pragma unroll
    for (int ni = 0; ni < 4; ++ni)
      bf[ni] = *(const bf16x8*)&Bsh[(wn + ni * 16 + lm) * 32 + kq8];
#pragma unroll
    for (int mi = 0; mi < 4; ++mi)
#pragma unroll
      for (int ni = 0; ni < 4; ++ni)
        acc[mi][ni] = __builtin_amdgcn_mfma_f32_16x16x32_bf16(af[mi], bf[ni], acc[mi][ni], 0, 0, 0);
  }

  float bcol[4];
#pragma unroll
  for (int ni = 0; ni < 4; ++ni)
    bcol[ni] = (bias && mode == 0) ? bias[n0 + wn + ni * 16 + lm] : 0.f;
  __syncthreads();
  float* epi = (float*)smem + w * 2048;
  float* Cf = (float*)Cv;
  u16* Cu = (u16*)Cv;
#pragma unroll
  for (int mi2 = 0; mi2 < 2; ++mi2) {
#pragma unroll
    for (int mm = 0; mm < 2; ++mm) {
      int mi = mi2 * 2 + mm;
#pragma unroll
      for (int ni = 0; ni < 4; ++ni)
#pragma unroll
        for (int r = 0; r < 4; ++r)
          epi[(mm * 16 + quad * 4 + r) * 64 + ni * 16 + lm] = acc[mi][ni][r] + bcol[ni];
    }
#pragma unroll
    for (int i = 0; i < 8; ++i) {
      int f = lane + 64 * i;
      int row = f >> 4, c4 = f & 15;
      int gr = m0 + wm + mi2 * 32 + row;
      int gc = n0 + wn + c4 * 4;
      size_t ci = (size_t)gr * ldc + gc;
      float4 v = *(const float4*)&epi[row * 64 + c4 * 4];
      if (mode == 0) {
        if (Rh) {
          ushort4 rh = *(const ushort4*)&Rh[ci];
          ushort4 rl = *(const ushort4*)&Rl[ci];
          v.x += bf2f(rh.x) + bf2f(rl.x); v.y += bf2f(rh.y) + bf2f(rl.y);
          v.z += bf2f(rh.z) + bf2f(rl.z); v.w += bf2f(rh.w) + bf2f(rl.w);
        }
        *(float4*)&Cf[ci] = v;
      } else if (mode == 2) {
        float4 o = *(const float4*)&Cf[ci];
        v.x += o.x; v.y += o.y; v.z += o.z; v.w += o.w;
        *(float4*)&Cf[ci] = v;
      } else {           // mode 4: gelu -> fp16 single
        ushort4 hv;
        hv.x = f2h(gelu_f(v.x)); hv.y = f2h(gelu_f(v.y));
        hv.z = f2h(gelu_f(v.z)); hv.w = f2h(gelu_f(v.w));
        *(ushort4*)&Cu[ci] = hv;
      }
    }
  }
}

// ============ async fp16 single-pass MFMA GEMM (O / W1 / W2, layers 1-2) ============
// A and W are fp16 planes.  mode 0: +bias +R(bf16 hi/lo) -> fp32 ;
// mode 2: fp32 += ; mode 4: gelu -> fp16 single plane.
__global__ __launch_bounds__(256) void mfma_f16_gemm_k(
    const u16* __restrict__ Ah, int lda,
    const u16* __restrict__ Wh, int ldwt,
    void* __restrict__ Cv, int ldc,
    const float* __restrict__ bias,
    const u16* __restrict__ Rh, const u16* __restrict__ Rl,
    int K, int mode)
{
  __shared__ __align__(16) char smem[32768];
  u16* Ash = (u16*)smem;
  u16* Bsh = Ash + 128 * 32;
  const int t = threadIdx.x;
  const int m0 = blockIdx.x * 128, n0 = blockIdx.y * 128;
  const int lane = t & 63, w = t >> 6;
  const int lrow = lane >> 2, lq = lane & 3;
  const int qg8 = (lq ^ ((lrow >> 1) & 3)) * 8;
  const int wm = (w & 1) * 64, wn = (w >> 1) * 64;
  const int lm = lane & 15, quad = lane >> 4;
  const int kq8 = (quad ^ ((lm >> 1) & 3)) * 8;

  f32x4 acc[4][4];
#pragma unroll
  for (int i = 0; i < 4; ++i)
#pragma unroll
    for (int j = 0; j < 4; ++j) acc[i][j] = (f32x4){0.f, 0.f, 0.f, 0.f};

  for (int k0 = 0; k0 < K; k0 += 32) {
    __syncthreads();
#pragma unroll
    for (int seg = 0; seg < 2; ++seg) {
      const int r0 = w * 32 + seg * 16;
      const size_t ga = (size_t)(m0 + r0 + lrow) * lda + k0 + qg8;
      const size_t gb = (size_t)(n0 + r0 + lrow) * ldwt + k0 + qg8;
      gll16(Ah + ga, &Ash[r0 * 32]);
      gll16(Wh + gb, &Bsh[r0 * 32]);
    }
    __syncthreads();

    f16x8 af[4], bf[4];
#pragma unroll
    for (int mi = 0; mi < 4; ++mi)
      af[mi] = *(const f16x8*)&Ash[(wm + mi * 16 + lm) * 32 + kq8];
#pragma unroll
    for (int ni = 0; ni < 4; ++ni)
      bf[ni] = *(const f16x8*)&Bsh[(wn + ni * 16 + lm) * 32 + kq8];
#pragma unroll
    for (int mi = 0; mi < 4; ++mi)
#pragma unroll
      for (int ni = 0; ni < 4; ++ni)
        acc[mi][ni] = __builtin_amdgcn_mfma_f32_16x16x32_f16(af[mi], bf[ni], acc[mi][ni], 0, 0, 0);
  }

  float bcol[4];
#pragma unroll
  for (int ni = 0; ni < 4; ++ni)
    bcol[ni] = (bias && mode == 0) ? bias[n0 + wn + ni * 16 + lm] : 0.f;
  __syncthreads();
  float* epi = (float*)smem + w * 2048;
  float* Cf = (float*)Cv;
  u16* Cu = (u16*)Cv;
#pragma unroll
  for (int mi2 = 0; mi2 < 2; ++mi2) {
#pragma unroll
    for (int mm = 0; mm < 2; ++mm) {
      int mi = mi2 * 2 + mm;
#pragma unroll
      for (int ni = 0; ni < 4; ++ni)
#pragma unroll
        for (int r = 0; r < 4; ++r)
          epi[(mm * 16 + quad * 4 + r) * 64 + ni * 16 + lm] = acc[mi][ni][r] + bcol[ni];
    }
#pragma unroll
    for (int i = 0; i < 8; ++i) {
      int f = lane + 64 * i;
      int row = f >> 4, c4 = f & 15;
      int gr = m0 + wm + mi2 * 32 + row;
      int gc = n0 + wn + c4 * 4;
      size_t ci = (size_t)gr * ldc + gc;
      float4 v = *(const float4*)&epi[row * 64 + c4 * 4];
      if (mode == 0) {
        if (Rh) {
          ushort4 rh = *(const ushort4*)&Rh[ci];
          ushort4 rl = *(const ushort4*)&Rl[ci];
          v.x += bf2f(rh.x) + bf2f(rl.x); v.y += bf2f(rh.y) + bf2f(rl.y);
          v.z += bf2f(rh.z) + bf2f(rl.z); v.w += bf2f(rh.w) + bf2f(rl.w);
        }
        *(float4*)&Cf[ci] = v;
      } else if (mode == 2) {
        float4 o = *(const float4*)&Cf[ci];
        v.x += o.x; v.y += o.y; v.z += o.z; v.w += o.w;
        *(float4*)&Cf[ci] = v;
      } else {           // mode 4: gelu -> fp16 single
        ushort4 hv;
        hv.x = f2h(gelu_f(v.x)); hv.y = f2h(gelu_f(v.y));
        hv.z = f2h(gelu_f(v.z)); hv.w = f2h(gelu_f(v.w));
        *(ushort4*)&Cu[ci] = hv;
      }
    }
  }
}

// ============ FFT-based autocorrelation ============
__global__ __launch_bounds__(256) void fftcorr_k(
    const float* __restrict__ q, const float* __restrict__ kv,
    float* __restrict__ Sre, float* __restrict__ Sim)
{
  __shared__ float zre[1024 * 9];
  __shared__ float zim[1024 * 9];
  __shared__ float twr[512];
  __shared__ float twi[512];
  const int t = threadIdx.x;
  const int b = blockIdx.y;
  const int d0 = blockIdx.x * 8;
  const int ch = t & 7, lidx = t >> 3;     // lidx in 0..31

  for (int k = t; k < 512; k += 256) {
    float ang = (float)k * 6.13592315154256e-3f;   // 2*pi/1024
    twr[k] = cosf(ang);
    twi[k] = -sinf(ang);
  }

  const size_t gbase = (((size_t)b << 10)) * D_ + d0 + ch;
  for (int it = 0; it < 32; ++it) {
    int l = (lidx << 5) + it;
    float qv = q[gbase + (size_t)l * D_];
    float kw = kv[gbase + (size_t)l * D_];
    int p = __brev((unsigned)l) >> 22;
    zre[p * 9 + ch] = qv;
    zim[p * 9 + ch] = kw;
  }
  __syncthreads();

  const int gg = t >> 3;                   // 0..31
#pragma unroll
  for (int s = 0; s < 10; s += 2) {
    const int m = 1 << s;
#pragma unroll
    for (int it2 = 0; it2 < 8; ++it2) {
      int g = gg + (it2 << 5);             // 0..255
      int wi_ = g & (m - 1);
      int base = ((g >> s) << (s + 2)) | wi_;
      int i0 = (base) * 9 + ch;
      int i1 = (base + m) * 9 + ch;
      int i2 = (base + 2 * m) * 9 + ch;
      int i3 = (base + 3 * m) * 9 + ch;
      int w1x = wi_ << (9 - s);
      int w2x = wi_ << (8 - s);
      int w2y = (wi_ + m) << (8 - s);
      float w1r = twr[w1x], w1i = twi[w1x];
      float w2ar = twr[w2x], w2ai = twi[w2x];
      float w2br = twr[w2y], w2bi = twi[w2y];
      float ar = zre[i0], ai = zim[i0];
      float br = zre[i1], bi = zim[i1];
      float cr = zre[i2], ci = zim[i2];
      float dr = zre[i3], di = zim[i3];
      float t1r = br * w1r - bi * w1i, t1i = br * w1i + bi * w1r;
      float u0r = ar + t1r, u0i = ai + t1i;
      float u1r = ar - t1r, u1i = ai - t1i;
      float t3r = dr * w1r - di * w1i, t3i = dr * w1i + di * w1r;
      float u2r = cr + t3r, u2i = ci + t3i;
      float u3r = cr - t3r, u3i = ci - t3i;
      float v0r = u2r * w2ar - u2i * w2ai, v0i = u2r * w2ai + u2i * w2ar;
      float v1r = u3r * w2br - u3i * w2bi, v1i = u3r * w2bi + u3i * w2br;
      zre[i0] = u0r + v0r; zim[i0] = u0i + v0i;
      zre[i2] = u0r - v0r; zim[i2] = u0i - v0i;
      zre[i1] = u1r + v1r; zim[i1] = u1i + v1i;
      zre[i3] = u1r - v1r; zim[i3] = u1i - v1i;
    }
    __syncthreads();
  }

  for (int it = 0; it <= 16; ++it) {
    int f = gg + (it << 5);
    if (f <= 512) {                        // uniform within each 8-lane octet
      int fm = (1024 - f) & 1023;
      float zr = zre[f * 9 + ch],  zi0 = zim[f * 9 + ch];
      float mr = zre[fm * 9 + ch], mi0 = zim[fm * 9 + ch];
      float Qr = 0.5f * (zr + mr),  Qi = 0.5f * (zi0 - mi0);
      float Kr = 0.5f * (zi0 + mi0), Ki = -0.5f * (zr - mr);
      float Pr = Qr * Kr + Qi * Ki;
      float Pi = Qi * Kr - Qr * Ki;
      Pr += __shfl_xor(Pr, 1); Pi += __shfl_xor(Pi, 1);
      Pr += __shfl_xor(Pr, 2); Pi += __shfl_xor(Pi, 2);
      Pr += __shfl_xor(Pr, 4); Pi += __shfl_xor(Pi, 4);
      if (ch == 0) {
        atomicAdd(&Sre[(b << 10) + f], Pr);
        atomicAdd(&Sim[(b << 10) + f], Pi);
      }
    }
  }
}

// ifft_topk_k: per-b inverse FFT + top-6 + softmax.  Self-cleans S.
__global__ __launch_bounds__(256) void ifft_topk_k(
    float* __restrict__ Sre, float* __restrict__ Sim,
    float* __restrict__ tc, int* __restrict__ dly)
{
  __shared__ float re[1024], im[1024];
  __shared__ float twr[512], twi[512];
  __shared__ float rv[256];
  __shared__ int ri[256];
  __shared__ float wsel[TOPK_];
  __shared__ int dsel[TOPK_];
  const int b = blockIdx.x, t = threadIdx.x;

  for (int k = t; k < 512; k += 256) {
    float ang = (float)k * 6.13592315154256e-3f;
    twr[k] = cosf(ang);
    twi[k] = sinf(ang);
  }
  for (int l = t; l < 1024; l += 256) {
    int f = (l <= 512) ? l : 1024 - l;
    float sr = Sre[(b << 10) + f];
    float si = Sim[(b << 10) + f];
    if (l > 512) si = -si;
    int p = __brev((unsigned)l) >> 22;
    re[p] = sr; im[p] = si;
  }
  __syncthreads();
  for (int f = t; f <= 512; f += 256) {
    Sre[(b << 10) + f] = 0.f;
    Sim[(b << 10) + f] = 0.f;
  }

#pragma unroll
  for (int s = 0; s < 10; s += 2) {
    const int m = 1 << s;
    int wi_ = t & (m - 1);
    int base = ((t >> s) << (s + 2)) | wi_;
    int i0 = base, i1 = base + m, i2 = base + 2 * m, i3 = base + 3 * m;
    int w1x = wi_ << (9 - s);
    int w2x = wi_ << (8 - s);
    int w2y = (wi_ + m) << (8 - s);
    float w1r = twr[w1x], w1i = twi[w1x];
    float w2ar = twr[w2x], w2ai = twi[w2x];
    float w2br = twr[w2y], w2bi = twi[w2y];
    float ar = re[i0], ai = im[i0];
    float br = re[i1], bi = im[i1];
    float cr = re[i2], ci = im[i2];
    float dr = re[i3], di = im[i3];
    float t1r = br * w1r - bi * w1i, t1i = br * w1i + bi * w1r;
    float u0r = ar + t1r, u0i = ai + t1i;
    float u1r = ar - t1r, u1i = ai - t1i;
    float t3r = dr * w1r - di * w1i, t3i = dr * w1i + di * w1r;
    float u2r = cr + t3r, u2i = ci + t3i;
    float u3r = cr - t3r, u3i = ci - t3i;
    float v0r = u2r * w2ar - u2i * w2ai, v0i = u2r * w2ai + u2i * w2ar;
    float v1r = u3r * w2br - u3i * w2bi, v1i = u3r * w2bi + u3i * w2br;
    re[i0] = u0r + v0r; im[i0] = u0i + v0i;
    re[i2] = u0r - v0r; im[i2] = u0i - v0i;
    re[i1] = u1r + v1r; im[i1] = u1i + v1i;
    re[i3] = u1r - v1r; im[i3] = u1i - v1i;
    __syncthreads();
  }

  const float scale = 1.0f / (1024.f * 512.f);
  for (int i = t; i < 1024; i += 256) re[i] *= scale;
  __syncthreads();

  for (int kk = 0; kk < TOPK_; ++kk) {
    float bv = -INFINITY; int bi = 0x7fffffff;
    for (int i = t; i < 1024; i += 256) {
      float v = re[i];
      if (v > bv) { bv = v; bi = i; }
    }
    rv[t] = bv; ri[t] = bi;
    __syncthreads();
    for (int s2 = 128; s2 > 0; s2 >>= 1) {
      if (t < s2) {
        if (rv[t + s2] > rv[t] || (rv[t + s2] == rv[t] && ri[t + s2] < ri[t])) {
          rv[t] = rv[t + s2]; ri[t] = ri[t + s2];
        }
      }
      __syncthreads();
    }
    if (t == 0) { wsel[kk] = rv[0]; dsel[kk] = ri[0]; re[ri[0]] = -INFINITY; }
    __syncthreads();
  }
  if (t == 0) {
    float m = wsel[0];
    float e[TOPK_], se = 0.f;
    for (int k = 0; k < TOPK_; ++k) { e[k] = expf(wsel[k] - m); se += e[k]; }
    for (int k = 0; k < TOPK_; ++k) {
      tc[b * TOPK_ + k] = e[k] / se;
      dly[b * TOPK_ + k] = dsel[k];
    }
  }
}

// ---------------- fp32 GEMM (final projection, fused col-mean subtract on A) ----------------
__global__ __launch_bounds__(256) void gemm_k(
    const float* __restrict__ A, int lda,
    const float* __restrict__ W, int ldw,
    float* __restrict__ C, int ldc,
    const float* __restrict__ bias,
    int K, const float* __restrict__ mu)
{
  __shared__ float As[TBK][TM + 4];
  __shared__ float Bs[TBK][TN + 4];
  const int t = threadIdx.x;
  const int m0 = blockIdx.x * TM;
  const int n0 = blockIdx.y * TN;
  const int tx = t & 15, ty = t >> 4;
  const int ar = t >> 2, akv = (t & 3) * 4;
  const int bkk = t >> 4, bc = (t & 15) * 4;
  const int mb = (m0 + ar) >> 10;          // batch of this A row
  float acc[4][4] = {};
  for (int k0 = 0; k0 < K; k0 += TBK) {
    float4 a4 = *(const float4*)&A[(size_t)(m0 + ar) * lda + (k0 + akv)];
    float4 w4 = *(const float4*)&W[(size_t)(k0 + bkk) * ldw + (n0 + bc)];
    if (mu) {
      float4 m4 = *(const float4*)&mu[(mb << 9) + k0 + akv];
      a4.x -= m4.x; a4.y -= m4.y; a4.z -= m4.z; a4.w -= m4.w;
    }
    __syncthreads();
    As[akv + 0][ar] = a4.x; As[akv + 1][ar] = a4.y;
    As[akv + 2][ar] = a4.z; As[akv + 3][ar] = a4.w;
    *(float4*)&Bs[bkk][bc] = w4;
    __syncthreads();
#pragma unroll
    for (int kk = 0; kk < TBK; ++kk) {
      float4 a = *(const float4*)&As[kk][ty * 4];
      float4 b = *(const float4*)&Bs[kk][tx * 4];
      float av[4] = {a.x, a.y, a.z, a.w};
      float bv[4] = {b.x, b.y, b.z, b.w};
#pragma unroll
      for (int i = 0; i < 4; ++i)
#pragma unroll
        for (int j = 0; j < 4; ++j) acc[i][j] += av[i] * bv[j];
    }
  }
#pragma unroll
  for (int i = 0; i < 4; ++i) {
    int m = m0 + ty * 4 + i;
    float* crow = &C[(size_t)m * ldc + (n0 + tx * 4)];
    float4 v = make_float4(acc[i][0], acc[i][1], acc[i][2], acc[i][3]);
    if (bias) {
      const float* bp = &bias[n0 + tx * 4];
      v.x += bp[0]; v.y += bp[1]; v.z += bp[2]; v.w += bp[3];
    }
    *(float4*)crow = v;
  }
}

// ---------------- embedding: circular conv1d(k=3), split-store to h planes ----------------
__global__ __launch_bounds__(256) void embed_k(
    const float* __restrict__ x, const float* __restrict__ W, u16* __restrict__ Ch)
{
  __shared__ float As[TBK][TM + 4];
  __shared__ float Bs[TBK][TN + 4];
  const int t = threadIdx.x;
  const int m0 = blockIdx.x * TM, n0 = blockIdx.y * TN;
  const int tx = t & 15, ty = t >> 4;
  const int ar = t >> 2, akv = (t & 3) * 4;
  const int bkk = t >> 4, bc = (t & 15) * 4;
  const int m = m0 + ar, mb = m >> 10, ml = m & (L_ - 1);
  float acc[4][4] = {};
  for (int k0 = 0; k0 < 3 * CIN_; k0 += TBK) {
    int kcol = k0 + akv;
    int j = kcol >> 6, c = kcol & 63;
    int lsrc = (ml + j - 1 + L_) & (L_ - 1);
    float4 a4 = *(const float4*)&x[((size_t)mb * L_ + lsrc) * CIN_ + c];
    float4 w4 = *(const float4*)&W[(size_t)(k0 + bkk) * D_ + (n0 + bc)];
    __syncthreads();
    As[akv + 0][ar] = a4.x; As[akv + 1][ar] = a4.y;
    As[akv + 2][ar] = a4.z; As[akv + 3][ar] = a4.w;
    *(float4*)&Bs[bkk][bc] = w4;
    __syncthreads();
#pragma unroll
    for (int kk = 0; kk < TBK; ++kk) {
      float4 a = *(const float4*)&As[kk][ty * 4];
      float4 b = *(const float4*)&Bs[kk][tx * 4];
      float av[4] = {a.x, a.y, a.z, a.w};
      float bv[4] = {b.x, b.y, b.z, b.w};
#pragma unroll
      for (int i = 0; i < 4; ++i)
#pragma unroll
        for (int jj = 0; jj < 4; ++jj) acc[i][jj] += av[i] * bv[jj];
    }
  }
#pragma unroll
  for (int i = 0; i < 4; ++i) {
    int mm = m0 + ty * 4 + i;
    size_t ci = (size_t)mm * D_ + (n0 + tx * 4);
    ushort4 hv, lv;
    unsigned int s0 = split2(acc[i][0]), s1 = split2(acc[i][1]);
    unsigned int s2 = split2(acc[i][2]), s3 = split2(acc[i][3]);
    hv.x = (u16)s0; hv.y = (u16)s1; hv.z = (u16)s2; hv.w = (u16)s3;
    lv.x = (u16)(s0 >> 16); lv.y = (u16)(s1 >> 16); lv.z = (u16)(s2 >> 16); lv.w = (u16)(s3 >> 16);
    *(ushort4*)&Ch[ci] = hv;
    *(ushort4*)&Ch[ci + NBLD_] = lv;
  }
}

// ------- weighted delay-gather: fp32 V -> split bf16 (layer 0) or fp16 single (lowp) -------
__global__ __launch_bounds__(256) void gather_k(const float* __restrict__ v,
    const float* __restrict__ tc, const int* __restrict__ dly, u16* __restrict__ out,
    int lowp)
{
  int tid = blockIdx.x * 256 + threadIdx.x;
  int c4 = tid & 127;
  int row = tid >> 7;
  int b = row >> 10, l = row & (L_ - 1);
  const float4* vb = (const float4*)(v + (size_t)b * L_ * D_);
  float4 o = make_float4(0.f, 0.f, 0.f, 0.f);
#pragma unroll
  for (int k = 0; k < TOPK_; ++k) {
    int ld = (l + dly[b * TOPK_ + k]) & (L_ - 1);
    float w = tc[b * TOPK_ + k];
    float4 vv = vb[(size_t)ld * (D_ / 4) + c4];
    o.x += w * vv.x; o.y += w * vv.y; o.z += w * vv.z; o.w += w * vv.w;
  }
  if (lowp) {
    ushort4 hv;
    hv.x = f2h(o.x); hv.y = f2h(o.y); hv.z = f2h(o.z); hv.w = f2h(o.w);
    *(ushort4*)&out[(size_t)tid * 4] = hv;
  } else {
    unsigned int s0 = split2(o.x), s1 = split2(o.y), s2 = split2(o.z), s3 = split2(o.w);
    ushort4 hv, lv;
    hv.x = (u16)s0; hv.y = (u16)s1; hv.z = (u16)s2; hv.w = (u16)s3;
    lv.x = (u16)(s0 >> 16); lv.y = (u16)(s1 >> 16); lv.z = (u16)(s2 >> 16); lv.w = (u16)(s3 >> 16);
    *(ushort4*)&out[(size_t)tid * 4] = hv;
    *(ushort4*)&out[(size_t)tid * 4 + NBLD_] = lv;
  }
}

// ------- series decomposition: fp32 in -> split bf16 h planes (+optional fp16 copy) -------
// Sliding-window 25-tap moving average (2 LDS reads/row, wave owns 32 rows).
__global__ __launch_bounds__(256) void decomp_k(const float* __restrict__ s,
                                                u16* __restrict__ outh,
                                                u16* __restrict__ outf)
{
  __shared__ float tile[152][64];
  const int t = threadIdx.x;
  const int l0 = blockIdx.x * 128, d0 = blockIdx.y * 64, b = blockIdx.z;
  const float* sb = s + (size_t)b * L_ * D_;
  for (int idx = t; idx < 152 * 16; idx += 256) {
    int row = idx >> 4, c4 = (idx & 15) * 4;
    int lsrc = l0 - 12 + row;
    lsrc = lsrc < 0 ? 0 : (lsrc > L_ - 1 ? L_ - 1 : lsrc);
    *(float4*)&tile[row][c4] = *(const float4*)&sb[(size_t)lsrc * D_ + d0 + c4];
  }
  __syncthreads();
  const int d = t & 63, lb = (t >> 6) * 32;
  float sum = 0.f;
#pragma unroll
  for (int j = 0; j < 25; ++j) sum += tile[lb + j][d];
  for (int it = 0; it < 32; ++it) {
    int lp = lb + it;
    float val = tile[lp + 12][d] - sum * (1.0f / 25.0f);
    unsigned int sp = split2(val);
    size_t ci = ((size_t)b * L_ + l0 + lp) * D_ + d0 + d;
    outh[ci] = (u16)(sp & 0xffffu);
    outh[ci + NBLD_] = (u16)(sp >> 16);
    if (outf) outf[ci] = f2h(val);
    if (it < 31) sum += tile[lp + 25][d] - tile[lp][d];
  }
}

// ---------------- LayerNorm over D: one wave per row, shuffle reduce ----------------
__global__ __launch_bounds__(256) void ln_k(const u16* __restrict__ ah,
    const float* __restrict__ g, const float* __restrict__ be, float* __restrict__ out)
{
  const int row = blockIdx.x * 4 + (threadIdx.x >> 6);
  const int lane = threadIdx.x & 63;
  const size_t base = (size_t)row * D_;
  uint4 hv = *(const uint4*)&ah[base + lane * 8];
  uint4 lv = *(const uint4*)&ah[base + lane * 8 + NBLD_];
  const unsigned int* hp = (const unsigned int*)&hv;
  const unsigned int* lp = (const unsigned int*)&lv;
  float x[8];
  float s = 0.f;
#pragma unroll
  for (int j = 0; j < 4; ++j) {
    float a0 = bf2f((u16)(hp[j] & 0xffffu)) + bf2f((u16)(lp[j] & 0xffffu));
    float a1 = bf2f((u16)(hp[j] >> 16)) + bf2f((u16)(lp[j] >> 16));
    x[2 * j] = a0; x[2 * j + 1] = a1; s += a0 + a1;
  }
#pragma unroll
  for (int o = 32; o > 0; o >>= 1) s += __shfl_xor(s, o);
  float mu = s * (1.0f / 512.0f);
  float v = 0.f;
#pragma unroll
  for (int j = 0; j < 8; ++j) { x[j] -= mu; v += x[j] * x[j]; }
#pragma unroll
  for (int o = 32; o > 0; o >>= 1) v += __shfl_xor(v, o);
  float rs = rsqrtf(v * (1.0f / 512.0f) + 1e-5f);
  float4 g0 = *(const float4*)&g[lane * 8];
  float4 g1 = *(const float4*)&g[lane * 8 + 4];
  float4 b0 = *(const float4*)&be[lane * 8];
  float4 b1 = *(const float4*)&be[lane * 8 + 4];
  float4 o0 = make_float4(x[0] * rs * g0.x + b0.x, x[1] * rs * g0.y + b0.y,
                          x[2] * rs * g0.z + b0.z, x[3] * rs * g0.w + b0.w);
  float4 o1 = make_float4(x[4] * rs * g1.x + b1.x, x[5] * rs * g1.y + b1.y,
                          x[6] * rs * g1.z + b1.z, x[7] * rs * g1.w + b1.w);
  *(float4*)&out[base + lane * 8] = o0;
  *(float4*)&out[base + lane * 8 + 4] = o1;
}

// ---------------- per-(b,d) time mean over L (256 blocks, no 2nd pass) ----------------
__global__ __launch_bounds__(256) void colmean_mu_k(const float* __restrict__ a,
                                                    float* __restrict__ mu)
{
  __shared__ float red[256];
  const int b = blockIdx.x, d0 = blockIdx.y * 64;
  const int d = threadIdx.x & 63, lg = threadIdx.x >> 6;
  const float* p = a + (size_t)b * L_ * D_ + d0 + d;
  float sum = 0.f;
  for (int l = lg; l < L_; l += 4) sum += p[(size_t)l * D_];
  red[threadIdx.x] = sum;
  __syncthreads();
  if (lg == 0) {
    float s = red[d] + red[d + 64] + red[d + 128] + red[d + 192];
    mu[(b << 9) + d0 + d] = s * (1.0f / 1024.0f);
  }
}

extern "C" void kernel_launch(void* const* d_in, const int* in_sizes, int n_in,
                              void* d_out, int out_size, void* d_ws, size_t ws_size,
                              hipStream_t stream) {
  (void)n_in; (void)in_sizes; (void)ws_size; (void)out_size;
  const float* x    = (const float*)d_in[0];
  const float* embw = (const float*)d_in[1];
  const float* wq   = (const float*)d_in[2];
  const float* bq   = (const float*)d_in[3];
  const float* wk   = (const float*)d_in[4];
  const float* bk   = (const float*)d_in[5];
  const float* wv   = (const float*)d_in[6];
  const float* bv   = (const float*)d_in[7];
  const float* wo   = (const float*)d_in[8];
  const float* bo   = (const float*)d_in[9];
  const float* w1   = (const float*)d_in[10];
  const float* w2   = (const float*)d_in[11];
  const float* lng  = (const float*)d_in[12];
  const float* lnb  = (const float*)d_in[13];
  const float* pw   = (const float*)d_in[14];
  const float* pb   = (const float*)d_in[15];

  const size_t nBLD = NBLD_;
  u16*   hh  = (u16*)d_ws;                       // h bf16 hi ; lo at +nBLD
  float* t0f = (float*)(hh + 2 * nBLD);
  float* t1f = t0f + nBLD;
  u16*   t1h = (u16*)t1f;
  float* Sre = t1f + nBLD;                       // spectrum accumulators (B x 1024)
  float* Sim = Sre + (size_t)B_ * L_;
  float* tc    = Sim + (size_t)B_ * L_;
  int*   dly   = (int*)(tc + B_ * TOPK_);
  u16* base = (u16*)(dly + B_ * TOPK_ + 64);
  const size_t nDD = (size_t)NL_ * D_ * D_, nDF = (size_t)NL_ * D_ * DFF_;
  u16* wqTh = base;             u16* wqTl = wqTh + nDD;
  u16* wkTh = wqTl + nDD;       u16* wkTl = wkTh + nDD;
  u16* wvTh = wkTl + nDD;       u16* wvTl = wvTh + nDD;
  u16* woTh = wvTl + nDD;       u16* woTl = woTh + nDD;
  u16* w1Th = woTl + nDD;       u16* w1Tl = w1Th + nDF;
  u16* w2Th = w1Tl + nDF;       u16* w2Tl = w2Th + nDF;
  // NOTE: layers >= 1 of wo / w1 / w2 hold fp16 content in their hi-plane
  // slots (transp_split_k f16_from=1); lo slots for those layers are unused.
  // The fp16 h copy for lowp FFN W1 lives in t1's lo half (t1h + nBLD),
  // which is dead for lowp layers (gather/u are fp16-single in the hi half;
  // the stale K fp32 upper bytes there were consumed by fftcorr already).
  // Workspace layout/size identical to the verified R8/R10 kernels.
  u16* h16 = t1h + nBLD;

  dim3 blk(256);
  const dim3 gGemm(512, 8);
  const dim3 gMfma(256, 4);
  const dim3 gMfma2(256, 4, 2);    // merged Q/K
  const dim3 gFft(64, B_);

  // batched weight transposes: z = layer; wo/w1/w2 layers>=1 become fp16 planes
  transp_split_k<<<dim3(16, 16, 3), blk, 0, stream>>>(wq, wqTh, wqTl, D_, D_, D_ * D_, 3);
  transp_split_k<<<dim3(16, 16, 3), blk, 0, stream>>>(wk, wkTh, wkTl, D_, D_, D_ * D_, 3);
  transp_split_k<<<dim3(16, 16, 3), blk, 0, stream>>>(wv, wvTh, wvTl, D_, D_, D_ * D_, 3);
  transp_split_k<<<dim3(16, 16, 3), blk, 0, stream>>>(wo, woTh, woTl, D_, D_, D_ * D_, 1);
  transp_split_k<<<dim3(16, 64, 3), blk, 0, stream>>>(w1, w1Th, w1Tl, D_, DFF_, D_ * DFF_, 1);
  transp_split_k<<<dim3(64, 16, 3), blk, 0, stream>>>(w2, w2Th, w2Tl, DFF_, D_, DFF_ * D_, 1);

  embed_k<<<gGemm, blk, 0, stream>>>(x, embw, hh);
  zero_k<<<dim3(256), blk, 0, stream>>>(Sre, 2 * B_ * L_);

  for (int l = 0; l < NL_; ++l) {
    // Q/K: split-bf16 everywhere (corr top-6 is a discrete selection).
    // V (reads h): layer 0,1 split; layer 2 plain bf16-hi.
    // O / W2 (read fp16 intermediates): layers 1,2 single-pass fp16.
    // W1 (reads h): layer 0 split; layers 1,2 fp16 via the h16 copy in t1-lo.
    const bool last = (l == NL_ - 1);
    const bool lowp = (l >= 1);
    const size_t oDD = (size_t)l * D_ * D_;
    const u16* hl = hh + nBLD;

    // merged Q (z=0) and K (z=1) projections -> fp32 (mode 0, no residual)
    mfma_split_gemm_k<<<gMfma2, blk, 0, stream>>>(hh, hl, D_, wqTh + oDD, wqTl + oDD, D_,
        t0f, D_, bq + (size_t)l * D_, nullptr, nullptr, D_, 0,
        wkTh + oDD, wkTl + oDD, t1f, bk + (size_t)l * D_);

    // FFT autocorrelation: forward+pack+accumulate, then iFFT fused with top-k
    fftcorr_k<<<gFft, blk, 0, stream>>>(t0f, t1f, Sre, Sim);
    ifft_topk_k<<<dim3(B_), blk, 0, stream>>>(Sre, Sim, tc, dly);

    // V -> t0f (fp32); gather -> t1 (split bf16 for l=0, fp16 single for l>=1)
    if (last)
      mfma_plain_gemm_k<<<gMfma, blk, 0, stream>>>(hh, D_, wvTh + oDD, D_,
          t0f, D_, bv + (size_t)l * D_, nullptr, nullptr, D_, 0);
    else
      mfma_split_gemm_k<<<gMfma, blk, 0, stream>>>(hh, hl, D_, wvTh + oDD, wvTl + oDD, D_,
          t0f, D_, bv + (size_t)l * D_, nullptr, nullptr, D_, 0,
          nullptr, nullptr, nullptr, nullptr);
    gather_k<<<dim3(16384), blk, 0, stream>>>(t0f, tc, dly, t1h, lowp ? 1 : 0);

    // out proj + bias + residual(h) -> t0f ; decomp -> h planes (+h16 for lowp FFN)
    if (lowp)
      mfma_f16_gemm_k<<<gMfma, blk, 0, stream>>>(t1h, D_, woTh + oDD, D_,
          t0f, D_, bo + (size_t)l * D_, hh, hl, D_, 0);
    else
      mfma_split_gemm_k<<<gMfma, blk, 0, stream>>>(t1h, t1h + nBLD, D_, woTh + oDD, woTl + oDD, D_,
          t0f, D_, bo + (size_t)l * D_, hh, hl, D_, 0,
          nullptr, nullptr, nullptr, nullptr);
    decomp_k<<<dim3(8, 8, B_), blk, 0, stream>>>(t0f, hh, lowp ? h16 : nullptr);

    // FFN: 2 M-chunks x 2 DFF-chunks.  u chunk (16384 x 1024) in t1-hi:
    // split bf16 (both halves) for l=0; fp16 single (hi half) for l>=1.
    for (int mc = 0; mc < 2; ++mc) {
      const size_t moff = (size_t)mc * 16384 * D_;
      for (int c = 0; c < 2; ++c) {
        const size_t o1 = (size_t)l * D_ * DFF_ + (size_t)c * 1024 * D_;
        const size_t o2 = (size_t)l * DFF_ * D_ + (size_t)c * 1024;
        // W1 (reads h or h16)
        if (lowp)
          mfma_f16_gemm_k<<<dim3(128, 8), blk, 0, stream>>>(h16 + moff, D_, w1Th + o1, D_,
              t1h, 1024, nullptr, nullptr, nullptr, D_, 4);
        else
          mfma_split_gemm_k<<<dim3(128, 8), blk, 0, stream>>>(hh + moff, hl + moff, D_,
              w1Th + o1, w1Tl + o1, D_, t1h, 1024, nullptr, nullptr, nullptr, D_, 1,
              nullptr, nullptr, nullptr, nullptr);
        // W2 (reads u)
        if (lowp) {
          if (c == 0)
            mfma_f16_gemm_k<<<dim3(128, 4), blk, 0, stream>>>(t1h, 1024, w2Th + o2, DFF_,
                t0f + moff, D_, nullptr, hh + moff, hl + moff, 1024, 0);
          else
            mfma_f16_gemm_k<<<dim3(128, 4), blk, 0, stream>>>(t1h, 1024, w2Th + o2, DFF_,
                t0f + moff, D_, nullptr, nullptr, nullptr, 1024, 2);
        } else {
          if (c == 0)
            mfma_split_gemm_k<<<dim3(128, 4), blk, 0, stream>>>(t1h, t1h + nBLD, 1024,
                w2Th + o2, w2Tl + o2, DFF_, t0f + moff, D_, nullptr, hh + moff, hl + moff, 1024, 0,
                nullptr, nullptr, nullptr, nullptr);
          else
            mfma_split_gemm_k<<<dim3(128, 4), blk, 0, stream>>>(t1h, t1h + nBLD, 1024,
                w2Th + o2, w2Tl + o2, DFF_, t0f + moff, D_, nullptr, nullptr, nullptr, 1024, 2,
                nullptr, nullptr, nullptr, nullptr);
        }
      }
    }
    decomp_k<<<dim3(8, 8, B_), blk, 0, stream>>>(t0f, hh, nullptr);
  }

  ln_k<<<dim3(B_ * L_ / 4), blk, 0, stream>>>(hh, lng, lnb, t0f);
  colmean_mu_k<<<dim3(B_, 8), blk, 0, stream>>>(t0f, t1f);     // mu (B x D) in t1f
  gemm_k<<<dim3(512, 1), blk, 0, stream>>>(t0f, D_, pw, CIN_, (float*)d_out, CIN_, pb, D_, t1f);
}

// Round 12
// 2593.842 us; speedup vs baseline: 1.1703x; 1.1703x over previous
//
#include <hip/hip_runtime.h>
#include <hip/hip_bf16.h>
#include <math.h>

#define B_   32
#define L_   1024
#define CIN_ 64
#define D_   512
#define DFF_ 2048
#define NL_  3
#define TOPK_ 6
#define NBLD_ ((size_t)B_ * L_ * D_)

#define TM 64
#define TN 64
#define TBK 16

typedef unsigned short u16;
typedef __bf16 bf16x8 __attribute__((ext_vector_type(8)));
typedef _Float16 f16x8 __attribute__((ext_vector_type(8)));
typedef float  f32x4  __attribute__((ext_vector_type(4)));

typedef const __attribute__((address_space(1))) void* gp1_t;
typedef __attribute__((address_space(3))) void* lp3_t;

__device__ __forceinline__ void gll16(const void* g, void* l) {
  __builtin_amdgcn_global_load_lds((gp1_t)g, (lp3_t)l, 16, 0, 0);
}

__device__ __forceinline__ float bf2f(u16 u) {
  return __uint_as_float(((unsigned int)u) << 16);
}
__device__ __forceinline__ u16 f2bf(float f) {
  unsigned int u = __float_as_uint(f);
  return (u16)((u + 0x7fffu + ((u >> 16) & 1u)) >> 16);   // RNE
}
__device__ __forceinline__ unsigned int split2(float f) {
  u16 hi = f2bf(f);
  u16 lo = f2bf(f - bf2f(hi));
  return (unsigned int)hi | ((unsigned int)lo << 16);
}
__device__ __forceinline__ u16 f2h(float f) {
  union { _Float16 h; u16 u; } cv;
  cv.h = (_Float16)f;                                      // v_cvt_f16_f32 RNE
  return cv.u;
}
__device__ __forceinline__ float gelu_f(float x) {
  return 0.5f * x * (1.0f + erff(x * 0.70710678118654752440f));
}

__global__ __launch_bounds__(256) void zero_k(float* __restrict__ p, int n) {
  int i = blockIdx.x * 256 + threadIdx.x;
  if (i < n) p[i] = 0.f;
}

// ------- weight transpose (z = layer): bf16x2 split planes, OR (z >= f16_from)
// an fp16 single plane written INTO the hi slot (lo slot untouched/unused).
__global__ __launch_bounds__(256) void transp_split_k(const float* __restrict__ W,
                                                      u16* __restrict__ WTh,
                                                      u16* __restrict__ WTl,
                                                      int K, int N, int stride,
                                                      int f16_from) {
  __shared__ float tile[32][33];
  const int z = blockIdx.z;
  W   += (size_t)z * stride;
  WTh += (size_t)z * stride;
  WTl += (size_t)z * stride;
  const int t = threadIdx.x;
  const int k0 = blockIdx.x * 32, n0 = blockIdx.y * 32;
  const int tx = t & 31, ty = t >> 5;
#pragma unroll
  for (int i = 0; i < 4; ++i) {
    int kk = ty + i * 8;
    tile[kk][tx] = W[(size_t)(k0 + kk) * N + n0 + tx];
  }
  __syncthreads();
#pragma unroll
  for (int i = 0; i < 4; ++i) {
    int nn = ty + i * 8;
    float v = tile[tx][nn];
    size_t o = (size_t)(n0 + nn) * K + k0 + tx;
    if (z >= f16_from) {
      WTh[o] = f2h(v);
    } else {
      unsigned int s = split2(v);
      WTh[o] = (u16)(s & 0xffffu);
      WTl[o] = (u16)(s >> 16);
    }
  }
}

// ============ async split MFMA GEMM with vectorized LDS-bounce epilogue ============
// mode 0: +bias +R(hi/lo) -> fp32 ; 1: gelu -> split ; 2: fp32 += ; 3: +bias -> split
// mode 4: gelu -> fp16 single plane.
// grid.z==2 selects (W2,C2,bias2) for z=1 (merged Q/K launch).
__global__ __launch_bounds__(256) void mfma_split_gemm_k(
    const u16* __restrict__ Ah, const u16* __restrict__ Al, int lda,
    const u16* Wh, const u16* Wl, int ldwt,
    void* Cv, int ldc,
    const float* bias,
    const u16* __restrict__ Rh, const u16* __restrict__ Rl,
    int K, int mode,
    const u16* W2h, const u16* W2l, void* C2v, const float* bias2)
{
  if (blockIdx.z == 1) { Wh = W2h; Wl = W2l; Cv = C2v; bias = bias2; }
  __shared__ __align__(16) char smem[32768];
  u16* Ash = (u16*)smem;
  u16* Asl = Ash + 128 * 32;
  u16* Bsh = Asl + 128 * 32;
  u16* Bsl = Bsh + 128 * 32;
  const int t = threadIdx.x;
  const int m0 = blockIdx.x * 128, n0 = blockIdx.y * 128;
  const int lane = t & 63, w = t >> 6;
  const int lrow = lane >> 2, lq = lane & 3;
  const int qg8 = (lq ^ ((lrow >> 1) & 3)) * 8;
  const int wm = (w & 1) * 64, wn = (w >> 1) * 64;
  const int lm = lane & 15, quad = lane >> 4;
  const int kq8 = (quad ^ ((lm >> 1) & 3)) * 8;

  f32x4 acc[4][4];
#pragma unroll
  for (int i = 0; i < 4; ++i)
#pragma unroll
    for (int j = 0; j < 4; ++j) acc[i][j] = (f32x4){0.f, 0.f, 0.f, 0.f};

  for (int k0 = 0; k0 < K; k0 += 32) {
    __syncthreads();
#pragma unroll
    for (int seg = 0; seg < 2; ++seg) {
      const int r0 = w * 32 + seg * 16;
      const size_t ga = (size_t)(m0 + r0 + lrow) * lda + k0 + qg8;
      const size_t gb = (size_t)(n0 + r0 + lrow) * ldwt + k0 + qg8;
      gll16(Ah + ga, &Ash[r0 * 32]);
      gll16(Al + ga, &Asl[r0 * 32]);
      gll16(Wh + gb, &Bsh[r0 * 32]);
      gll16(Wl + gb, &Bsl[r0 * 32]);
    }
    __syncthreads();

    bf16x8 afh[4], afl[4], bfh[4], bfl[4];
#pragma unroll
    for (int mi = 0; mi < 4; ++mi) {
      afh[mi] = *(const bf16x8*)&Ash[(wm + mi * 16 + lm) * 32 + kq8];
      afl[mi] = *(const bf16x8*)&Asl[(wm + mi * 16 + lm) * 32 + kq8];
    }
#pragma unroll
    for (int ni = 0; ni < 4; ++ni) {
      bfh[ni] = *(const bf16x8*)&Bsh[(wn + ni * 16 + lm) * 32 + kq8];
      bfl[ni] = *(const bf16x8*)&Bsl[(wn + ni * 16 + lm) * 32 + kq8];
    }
#pragma unroll
    for (int mi = 0; mi < 4; ++mi)
#pragma unroll
      for (int ni = 0; ni < 4; ++ni) {
        acc[mi][ni] = __builtin_amdgcn_mfma_f32_16x16x32_bf16(afh[mi], bfh[ni], acc[mi][ni], 0, 0, 0);
        acc[mi][ni] = __builtin_amdgcn_mfma_f32_16x16x32_bf16(afh[mi], bfl[ni], acc[mi][ni], 0, 0, 0);
        acc[mi][ni] = __builtin_amdgcn_mfma_f32_16x16x32_bf16(afl[mi], bfh[ni], acc[mi][ni], 0, 0, 0);
      }
  }

  // -------- vectorized epilogue: per-wave LDS bounce (2 rounds of 32x64) --------
  float bcol[4];
#pragma unroll
  for (int ni = 0; ni < 4; ++ni)
    bcol[ni] = (bias && (mode == 0 || mode == 3)) ? bias[n0 + wn + ni * 16 + lm] : 0.f;
  __syncthreads();                       // all staging reads done before aliasing
  float* epi = (float*)smem + w * 2048;  // 8KB per wave
  float* Cf = (float*)Cv;
  u16* Cu = (u16*)Cv;
#pragma unroll
  for (int mi2 = 0; mi2 < 2; ++mi2) {
#pragma unroll
    for (int mm = 0; mm < 2; ++mm) {
      int mi = mi2 * 2 + mm;
#pragma unroll
      for (int ni = 0; ni < 4; ++ni)
#pragma unroll
        for (int r = 0; r < 4; ++r)
          epi[(mm * 16 + quad * 4 + r) * 64 + ni * 16 + lm] = acc[mi][ni][r] + bcol[ni];
    }
#pragma unroll
    for (int i = 0; i < 8; ++i) {
      int f = lane + 64 * i;
      int row = f >> 4, c4 = f & 15;
      int gr = m0 + wm + mi2 * 32 + row;
      int gc = n0 + wn + c4 * 4;
      size_t ci = (size_t)gr * ldc + gc;
      float4 v = *(const float4*)&epi[row * 64 + c4 * 4];
      if (mode == 0) {
        if (Rh) {
          ushort4 rh = *(const ushort4*)&Rh[ci];
          ushort4 rl = *(const ushort4*)&Rl[ci];
          v.x += bf2f(rh.x) + bf2f(rl.x); v.y += bf2f(rh.y) + bf2f(rl.y);
          v.z += bf2f(rh.z) + bf2f(rl.z); v.w += bf2f(rh.w) + bf2f(rl.w);
        }
        *(float4*)&Cf[ci] = v;
      } else if (mode == 2) {
        float4 o = *(const float4*)&Cf[ci];
        v.x += o.x; v.y += o.y; v.z += o.z; v.w += o.w;
        *(float4*)&Cf[ci] = v;
      } else if (mode == 4) {
        ushort4 hv;
        hv.x = f2h(gelu_f(v.x)); hv.y = f2h(gelu_f(v.y));
        hv.z = f2h(gelu_f(v.z)); hv.w = f2h(gelu_f(v.w));
        *(ushort4*)&Cu[ci] = hv;
      } else {
        if (mode == 1) { v.x = gelu_f(v.x); v.y = gelu_f(v.y); v.z = gelu_f(v.z); v.w = gelu_f(v.w); }
        unsigned int s0 = split2(v.x), s1 = split2(v.y), s2 = split2(v.z), s3 = split2(v.w);
        ushort4 hv, lv;
        hv.x = (u16)s0; hv.y = (u16)s1; hv.z = (u16)s2; hv.w = (u16)s3;
        lv.x = (u16)(s0 >> 16); lv.y = (u16)(s1 >> 16); lv.z = (u16)(s2 >> 16); lv.w = (u16)(s3 >> 16);
        *(ushort4*)&Cu[ci] = hv;
        *(ushort4*)&Cu[ci + NBLD_] = lv;
      }
    }
  }
}

// ============ async plain bf16 MFMA GEMM (hi planes; last-layer V) ============
// mode 0: +bias +R -> fp32 ; mode 2: fp32 += ; mode 4: gelu -> fp16 single.
__global__ __launch_bounds__(256) void mfma_plain_gemm_k(
    const u16* __restrict__ Ah, int lda,
    const u16* __restrict__ Wh, int ldwt,
    void* __restrict__ Cv, int ldc,
    const float* __restrict__ bias,
    const u16* __restrict__ Rh, const u16* __restrict__ Rl,
    int K, int mode)
{
  __shared__ __align__(16) char smem[32768];
  u16* Ash = (u16*)smem;
  u16* Bsh = Ash + 128 * 32;
  const int t = threadIdx.x;
  const int m0 = blockIdx.x * 128, n0 = blockIdx.y * 128;
  const int lane = t & 63, w = t >> 6;
  const int lrow = lane >> 2, lq = lane & 3;
  const int qg8 = (lq ^ ((lrow >> 1) & 3)) * 8;
  const int wm = (w & 1) * 64, wn = (w >> 1) * 64;
  const int lm = lane & 15, quad = lane >> 4;
  const int kq8 = (quad ^ ((lm >> 1) & 3)) * 8;

  f32x4 acc[4][4];
#pragma unroll
  for (int i = 0; i < 4; ++i)
#pragma unroll
    for (int j = 0; j < 4; ++j) acc[i][j] = (f32x4){0.f, 0.f, 0.f, 0.f};

  for (int k0 = 0; k0 < K; k0 += 32) {
    __syncthreads();
#pragma unroll
    for (int seg = 0; seg < 2; ++seg) {
      const int r0 = w * 32 + seg * 16;
      const size_t ga = (size_t)(m0 + r0 + lrow) * lda + k0 + qg8;
      const size_t gb = (size_t)(n0 + r0 + lrow) * ldwt + k0 + qg8;
      gll16(Ah + ga, &Ash[r0 * 32]);
      gll16(Wh + gb, &Bsh[r0 * 32]);
    }
    __syncthreads();

    bf16x8 af[4], bf[4];
#pragma unroll
    for (int mi = 0; mi < 4; ++mi)
      af[mi] = *(const bf16x8*)&Ash[(wm + mi * 16 + lm) * 32 + kq8];
#pragma unroll
    for (int ni = 0; ni < 4; ++ni)
      bf[ni] = *(const bf16x8*)&Bsh[(wn + ni * 16 + lm) * 32 + kq8];
#pragma unroll
    for (int mi = 0; mi < 4; ++mi)
#pragma unroll
      for (int ni = 0; ni < 4; ++ni)
        acc[mi][ni] = __builtin_amdgcn_mfma_f32_16x16x32_bf16(af[mi], bf[ni], acc[mi][ni], 0, 0, 0);
  }

  float bcol[4];
#pragma unroll
  for (int ni = 0; ni < 4; ++ni)
    bcol[ni] = (bias && mode == 0) ? bias[n0 + wn + ni * 16 + lm] : 0.f;
  __syncthreads();
  float* epi = (float*)smem + w * 2048;
  float* Cf = (float*)Cv;
  u16* Cu = (u16*)Cv;
#pragma unroll
  for (int mi2 = 0; mi2 < 2; ++mi2) {
#pragma unroll
    for (int mm = 0; mm < 2; ++mm) {
      int mi = mi2 * 2 + mm;
#pragma unroll
      for (int ni = 0; ni < 4; ++ni)
#pragma unroll
        for (int r = 0; r < 4; ++r)
          epi[(mm * 16 + quad * 4 + r) * 64 + ni * 16 + lm] = acc[mi][ni][r] + bcol[ni];
    }
#pragma unroll
    for (int i = 0; i < 8; ++i) {
      int f = lane + 64 * i;
      int row = f >> 4, c4 = f & 15;
      int gr = m0 + wm + mi2 * 32 + row;
      int gc = n0 + wn + c4 * 4;
      size_t ci = (size_t)gr * ldc + gc;
      float4 v = *(const float4*)&epi[row * 64 + c4 * 4];
      if (mode == 0) {
        if (Rh) {
          ushort4 rh = *(const ushort4*)&Rh[ci];
          ushort4 rl = *(const ushort4*)&Rl[ci];
          v.x += bf2f(rh.x) + bf2f(rl.x); v.y += bf2f(rh.y) + bf2f(rl.y);
          v.z += bf2f(rh.z) + bf2f(rl.z); v.w += bf2f(rh.w) + bf2f(rl.w);
        }
        *(float4*)&Cf[ci] = v;
      } else if (mode == 2) {
        float4 o = *(const float4*)&Cf[ci];
        v.x += o.x; v.y += o.y; v.z += o.z; v.w += o.w;
        *(float4*)&Cf[ci] = v;
      } else {           // mode 4: gelu -> fp16 single
        ushort4 hv;
        hv.x = f2h(gelu_f(v.x)); hv.y = f2h(gelu_f(v.y));
        hv.z = f2h(gelu_f(v.z)); hv.w = f2h(gelu_f(v.w));
        *(ushort4*)&Cu[ci] = hv;
      }
    }
  }
}

// ============ async fp16 single-pass MFMA GEMM (O / W1 / W2, all layers) ============
// A and W are fp16 planes.  mode 0: +bias +R(bf16 hi/lo) -> fp32 ;
// mode 2: fp32 += ; mode 4: gelu -> fp16 single plane.
__global__ __launch_bounds__(256) void mfma_f16_gemm_k(
    const u16* __restrict__ Ah, int lda,
    const u16* __restrict__ Wh, int ldwt,
    void* __restrict__ Cv, int ldc,
    const float* __restrict__ bias,
    const u16* __restrict__ Rh, const u16* __restrict__ Rl,
    int K, int mode)
{
  __shared__ __align__(16) char smem[32768];
  u16* Ash = (u16*)smem;
  u16* Bsh = Ash + 128 * 32;
  const int t = threadIdx.x;
  const int m0 = blockIdx.x * 128, n0 = blockIdx.y * 128;
  const int lane = t & 63, w = t >> 6;
  const int lrow = lane >> 2, lq = lane & 3;
  const int qg8 = (lq ^ ((lrow >> 1) & 3)) * 8;
  const int wm = (w & 1) * 64, wn = (w >> 1) * 64;
  const int lm = lane & 15, quad = lane >> 4;
  const int kq8 = (quad ^ ((lm >> 1) & 3)) * 8;

  f32x4 acc[4][4];
#pragma unroll
  for (int i = 0; i < 4; ++i)
#pragma unroll
    for (int j = 0; j < 4; ++j) acc[i][j] = (f32x4){0.f, 0.f, 0.f, 0.f};

  for (int k0 = 0; k0 < K; k0 += 32) {
    __syncthreads();
#pragma unroll
    for (int seg = 0; seg < 2; ++seg) {
      const int r0 = w * 32 + seg * 16;
      const size_t ga = (size_t)(m0 + r0 + lrow) * lda + k0 + qg8;
      const size_t gb = (size_t)(n0 + r0 + lrow) * ldwt + k0 + qg8;
      gll16(Ah + ga, &Ash[r0 * 32]);
      gll16(Wh + gb, &Bsh[r0 * 32]);
    }
    __syncthreads();

    f16x8 af[4], bf[4];
#pragma unroll
    for (int mi = 0; mi < 4; ++mi)
      af[mi] = *(const f16x8*)&Ash[(wm + mi * 16 + lm) * 32 + kq8];
#pragma unroll
    for (int ni = 0; ni < 4; ++ni)
      bf[ni] = *(const f16x8*)&Bsh[(wn + ni * 16 + lm) * 32 + kq8];
#pragma unroll
    for (int mi = 0; mi < 4; ++mi)
#pragma unroll
      for (int ni = 0; ni < 4; ++ni)
        acc[mi][ni] = __builtin_amdgcn_mfma_f32_16x16x32_f16(af[mi], bf[ni], acc[mi][ni], 0, 0, 0);
  }

  float bcol[4];
#pragma unroll
  for (int ni = 0; ni < 4; ++ni)
    bcol[ni] = (bias && mode == 0) ? bias[n0 + wn + ni * 16 + lm] : 0.f;
  __syncthreads();
  float* epi = (float*)smem + w * 2048;
  float* Cf = (float*)Cv;
  u16* Cu = (u16*)Cv;
#pragma unroll
  for (int mi2 = 0; mi2 < 2; ++mi2) {
#pragma unroll
    for (int mm = 0; mm < 2; ++mm) {
      int mi = mi2 * 2 + mm;
#pragma unroll
      for (int ni = 0; ni < 4; ++ni)
#pragma unroll
        for (int r = 0; r < 4; ++r)
          epi[(mm * 16 + quad * 4 + r) * 64 + ni * 16 + lm] = acc[mi][ni][r] + bcol[ni];
    }
#pragma unroll
    for (int i = 0; i < 8; ++i) {
      int f = lane + 64 * i;
      int row = f >> 4, c4 = f & 15;
      int gr = m0 + wm + mi2 * 32 + row;
      int gc = n0 + wn + c4 * 4;
      size_t ci = (size_t)gr * ldc + gc;
      float4 v = *(const float4*)&epi[row * 64 + c4 * 4];
      if (mode == 0) {
        if (Rh) {
          ushort4 rh = *(const ushort4*)&Rh[ci];
          ushort4 rl = *(const ushort4*)&Rl[ci];
          v.x += bf2f(rh.x) + bf2f(rl.x); v.y += bf2f(rh.y) + bf2f(rl.y);
          v.z += bf2f(rh.z) + bf2f(rl.z); v.w += bf2f(rh.w) + bf2f(rl.w);
        }
        *(float4*)&Cf[ci] = v;
      } else if (mode == 2) {
        float4 o = *(const float4*)&Cf[ci];
        v.x += o.x; v.y += o.y; v.z += o.z; v.w += o.w;
        *(float4*)&Cf[ci] = v;
      } else {           // mode 4: gelu -> fp16 single
        ushort4 hv;
        hv.x = f2h(gelu_f(v.x)); hv.y = f2h(gelu_f(v.y));
        hv.z = f2h(gelu_f(v.z)); hv.w = f2h(gelu_f(v.w));
        *(ushort4*)&Cu[ci] = hv;
      }
    }
  }
}

// ============ FFT-based autocorrelation ============
__global__ __launch_bounds__(256) void fftcorr_k(
    const float* __restrict__ q, const float* __restrict__ kv,
    float* __restrict__ Sre, float* __restrict__ Sim)
{
  __shared__ float zre[1024 * 9];
  __shared__ float zim[1024 * 9];
  __shared__ float twr[512];
  __shared__ float twi[512];
  const int t = threadIdx.x;
  const int b = blockIdx.y;
  const int d0 = blockIdx.x * 8;
  const int ch = t & 7, lidx = t >> 3;     // lidx in 0..31

  for (int k = t; k < 512; k += 256) {
    float ang = (float)k * 6.13592315154256e-3f;   // 2*pi/1024
    twr[k] = cosf(ang);
    twi[k] = -sinf(ang);
  }

  const size_t gbase = (((size_t)b << 10)) * D_ + d0 + ch;
  for (int it = 0; it < 32; ++it) {
    int l = (lidx << 5) + it;
    float qv = q[gbase + (size_t)l * D_];
    float kw = kv[gbase + (size_t)l * D_];
    int p = __brev((unsigned)l) >> 22;
    zre[p * 9 + ch] = qv;
    zim[p * 9 + ch] = kw;
  }
  __syncthreads();

  const int gg = t >> 3;                   // 0..31
#pragma unroll
  for (int s = 0; s < 10; s += 2) {
    const int m = 1 << s;
#pragma unroll
    for (int it2 = 0; it2 < 8; ++it2) {
      int g = gg + (it2 << 5);             // 0..255
      int wi_ = g & (m - 1);
      int base = ((g >> s) << (s + 2)) | wi_;
      int i0 = (base) * 9 + ch;
      int i1 = (base + m) * 9 + ch;
      int i2 = (base + 2 * m) * 9 + ch;
      int i3 = (base + 3 * m) * 9 + ch;
      int w1x = wi_ << (9 - s);
      int w2x = wi_ << (8 - s);
      int w2y = (wi_ + m) << (8 - s);
      float w1r = twr[w1x], w1i = twi[w1x];
      float w2ar = twr[w2x], w2ai = twi[w2x];
      float w2br = twr[w2y], w2bi = twi[w2y];
      float ar = zre[i0], ai = zim[i0];
      float br = zre[i1], bi = zim[i1];
      float cr = zre[i2], ci = zim[i2];
      float dr = zre[i3], di = zim[i3];
      float t1r = br * w1r - bi * w1i, t1i = br * w1i + bi * w1r;
      float u0r = ar + t1r, u0i = ai + t1i;
      float u1r = ar - t1r, u1i = ai - t1i;
      float t3r = dr * w1r - di * w1i, t3i = dr * w1i + di * w1r;
      float u2r = cr + t3r, u2i = ci + t3i;
      float u3r = cr - t3r, u3i = ci - t3i;
      float v0r = u2r * w2ar - u2i * w2ai, v0i = u2r * w2ai + u2i * w2ar;
      float v1r = u3r * w2br - u3i * w2bi, v1i = u3r * w2bi + u3i * w2br;
      zre[i0] = u0r + v0r; zim[i0] = u0i + v0i;
      zre[i2] = u0r - v0r; zim[i2] = u0i - v0i;
      zre[i1] = u1r + v1r; zim[i1] = u1i + v1i;
      zre[i3] = u1r - v1r; zim[i3] = u1i - v1i;
    }
    __syncthreads();
  }

  for (int it = 0; it <= 16; ++it) {
    int f = gg + (it << 5);
    if (f <= 512) {                        // uniform within each 8-lane octet
      int fm = (1024 - f) & 1023;
      float zr = zre[f * 9 + ch],  zi0 = zim[f * 9 + ch];
      float mr = zre[fm * 9 + ch], mi0 = zim[fm * 9 + ch];
      float Qr = 0.5f * (zr + mr),  Qi = 0.5f * (zi0 - mi0);
      float Kr = 0.5f * (zi0 + mi0), Ki = -0.5f * (zr - mr);
      float Pr = Qr * Kr + Qi * Ki;
      float Pi = Qi * Kr - Qr * Ki;
      Pr += __shfl_xor(Pr, 1); Pi += __shfl_xor(Pi, 1);
      Pr += __shfl_xor(Pr, 2); Pi += __shfl_xor(Pi, 2);
      Pr += __shfl_xor(Pr, 4); Pi += __shfl_xor(Pi, 4);
      if (ch == 0) {
        atomicAdd(&Sre[(b << 10) + f], Pr);
        atomicAdd(&Sim[(b << 10) + f], Pi);
      }
    }
  }
}

// ifft_topk_k: per-b inverse FFT + top-6 + softmax.  Self-cleans S.
__global__ __launch_bounds__(256) void ifft_topk_k(
    float* __restrict__ Sre, float* __restrict__ Sim,
    float* __restrict__ tc, int* __restrict__ dly)
{
  __shared__ float re[1024], im[1024];
  __shared__ float twr[512], twi[512];
  __shared__ float rv[256];
  __shared__ int ri[256];
  __shared__ float wsel[TOPK_];
  __shared__ int dsel[TOPK_];
  const int b = blockIdx.x, t = threadIdx.x;

  for (int k = t; k < 512; k += 256) {
    float ang = (float)k * 6.13592315154256e-3f;
    twr[k] = cosf(ang);
    twi[k] = sinf(ang);
  }
  for (int l = t; l < 1024; l += 256) {
    int f = (l <= 512) ? l : 1024 - l;
    float sr = Sre[(b << 10) + f];
    float si = Sim[(b << 10) + f];
    if (l > 512) si = -si;
    int p = __brev((unsigned)l) >> 22;
    re[p] = sr; im[p] = si;
  }
  __syncthreads();
  for (int f = t; f <= 512; f += 256) {
    Sre[(b << 10) + f] = 0.f;
    Sim[(b << 10) + f] = 0.f;
  }

#pragma unroll
  for (int s = 0; s < 10; s += 2) {
    const int m = 1 << s;
    int wi_ = t & (m - 1);
    int base = ((t >> s) << (s + 2)) | wi_;
    int i0 = base, i1 = base + m, i2 = base + 2 * m, i3 = base + 3 * m;
    int w1x = wi_ << (9 - s);
    int w2x = wi_ << (8 - s);
    int w2y = (wi_ + m) << (8 - s);
    float w1r = twr[w1x], w1i = twi[w1x];
    float w2ar = twr[w2x], w2ai = twi[w2x];
    float w2br = twr[w2y], w2bi = twi[w2y];
    float ar = re[i0], ai = im[i0];
    float br = re[i1], bi = im[i1];
    float cr = re[i2], ci = im[i2];
    float dr = re[i3], di = im[i3];
    float t1r = br * w1r - bi * w1i, t1i = br * w1i + bi * w1r;
    float u0r = ar + t1r, u0i = ai + t1i;
    float u1r = ar - t1r, u1i = ai - t1i;
    float t3r = dr * w1r - di * w1i, t3i = dr * w1i + di * w1r;
    float u2r = cr + t3r, u2i = ci + t3i;
    float u3r = cr - t3r, u3i = ci - t3i;
    float v0r = u2r * w2ar - u2i * w2ai, v0i = u2r * w2ai + u2i * w2ar;
    float v1r = u3r * w2br - u3i * w2bi, v1i = u3r * w2bi + u3i * w2br;
    re[i0] = u0r + v0r; im[i0] = u0i + v0i;
    re[i2] = u0r - v0r; im[i2] = u0i - v0i;
    re[i1] = u1r + v1r; im[i1] = u1i + v1i;
    re[i3] = u1r - v1r; im[i3] = u1i - v1i;
    __syncthreads();
  }

  const float scale = 1.0f / (1024.f * 512.f);
  for (int i = t; i < 1024; i += 256) re[i] *= scale;
  __syncthreads();

  for (int kk = 0; kk < TOPK_; ++kk) {
    float bv = -INFINITY; int bi = 0x7fffffff;
    for (int i = t; i < 1024; i += 256) {
      float v = re[i];
      if (v > bv) { bv = v; bi = i; }
    }
    rv[t] = bv; ri[t] = bi;
    __syncthreads();
    for (int s2 = 128; s2 > 0; s2 >>= 1) {
      if (t < s2) {
        if (rv[t + s2] > rv[t] || (rv[t + s2] == rv[t] && ri[t + s2] < ri[t])) {
          rv[t] = rv[t + s2]; ri[t] = ri[t + s2];
        }
      }
      __syncthreads();
    }
    if (t == 0) { wsel[kk] = rv[0]; dsel[kk] = ri[0]; re[ri[0]] = -INFINITY; }
    __syncthreads();
  }
  if (t == 0) {
    float m = wsel[0];
    float e[TOPK_], se = 0.f;
    for (int k = 0; k < TOPK_; ++k) { e[k] = expf(wsel[k] - m); se += e[k]; }
    for (int k = 0; k < TOPK_; ++k) {
      tc[b * TOPK_ + k] = e[k] / se;
      dly[b * TOPK_ + k] = dsel[k];
    }
  }
}

// ---------------- fp32 GEMM (final projection, fused col-mean subtract on A) ----------------
__global__ __launch_bounds__(256) void gemm_k(
    const float* __restrict__ A, int lda,
    const float* __restrict__ W, int ldw,
    float* __restrict__ C, int ldc,
    const float* __restrict__ bias,
    int K, const float* __restrict__ mu)
{
  __shared__ float As[TBK][TM + 4];
  __shared__ float Bs[TBK][TN + 4];
  const int t = threadIdx.x;
  const int m0 = blockIdx.x * TM;
  const int n0 = blockIdx.y * TN;
  const int tx = t & 15, ty = t >> 4;
  const int ar = t >> 2, akv = (t & 3) * 4;
  const int bkk = t >> 4, bc = (t & 15) * 4;
  const int mb = (m0 + ar) >> 10;          // batch of this A row
  float acc[4][4] = {};
  for (int k0 = 0; k0 < K; k0 += TBK) {
    float4 a4 = *(const float4*)&A[(size_t)(m0 + ar) * lda + (k0 + akv)];
    float4 w4 = *(const float4*)&W[(size_t)(k0 + bkk) * ldw + (n0 + bc)];
    if (mu) {
      float4 m4 = *(const float4*)&mu[(mb << 9) + k0 + akv];
      a4.x -= m4.x; a4.y -= m4.y; a4.z -= m4.z; a4.w -= m4.w;
    }
    __syncthreads();
    As[akv + 0][ar] = a4.x; As[akv + 1][ar] = a4.y;
    As[akv + 2][ar] = a4.z; As[akv + 3][ar] = a4.w;
    *(float4*)&Bs[bkk][bc] = w4;
    __syncthreads();
#pragma unroll
    for (int kk = 0; kk < TBK; ++kk) {
      float4 a = *(const float4*)&As[kk][ty * 4];
      float4 b = *(const float4*)&Bs[kk][tx * 4];
      float av[4] = {a.x, a.y, a.z, a.w};
      float bv[4] = {b.x, b.y, b.z, b.w};
#pragma unroll
      for (int i = 0; i < 4; ++i)
#pragma unroll
        for (int j = 0; j < 4; ++j) acc[i][j] += av[i] * bv[j];
    }
  }
#pragma unroll
  for (int i = 0; i < 4; ++i) {
    int m = m0 + ty * 4 + i;
    float* crow = &C[(size_t)m * ldc + (n0 + tx * 4)];
    float4 v = make_float4(acc[i][0], acc[i][1], acc[i][2], acc[i][3]);
    if (bias) {
      const float* bp = &bias[n0 + tx * 4];
      v.x += bp[0]; v.y += bp[1]; v.z += bp[2]; v.w += bp[3];
    }
    *(float4*)crow = v;
  }
}

// ---------------- embedding: circular conv1d(k=3), split-store to h planes ----------------
__global__ __launch_bounds__(256) void embed_k(
    const float* __restrict__ x, const float* __restrict__ W, u16* __restrict__ Ch)
{
  __shared__ float As[TBK][TM + 4];
  __shared__ float Bs[TBK][TN + 4];
  const int t = threadIdx.x;
  const int m0 = blockIdx.x * TM, n0 = blockIdx.y * TN;
  const int tx = t & 15, ty = t >> 4;
  const int ar = t >> 2, akv = (t & 3) * 4;
  const int bkk = t >> 4, bc = (t & 15) * 4;
  const int m = m0 + ar, mb = m >> 10, ml = m & (L_ - 1);
  float acc[4][4] = {};
  for (int k0 = 0; k0 < 3 * CIN_; k0 += TBK) {
    int kcol = k0 + akv;
    int j = kcol >> 6, c = kcol & 63;
    int lsrc = (ml + j - 1 + L_) & (L_ - 1);
    float4 a4 = *(const float4*)&x[((size_t)mb * L_ + lsrc) * CIN_ + c];
    float4 w4 = *(const float4*)&W[(size_t)(k0 + bkk) * D_ + (n0 + bc)];
    __syncthreads();
    As[akv + 0][ar] = a4.x; As[akv + 1][ar] = a4.y;
    As[akv + 2][ar] = a4.z; As[akv + 3][ar] = a4.w;
    *(float4*)&Bs[bkk][bc] = w4;
    __syncthreads();
#pragma unroll
    for (int kk = 0; kk < TBK; ++kk) {
      float4 a = *(const float4*)&As[kk][ty * 4];
      float4 b = *(const float4*)&Bs[kk][tx * 4];
      float av[4] = {a.x, a.y, a.z, a.w};
      float bv[4] = {b.x, b.y, b.z, b.w};
#pragma unroll
      for (int i = 0; i < 4; ++i)
#pragma unroll
        for (int jj = 0; jj < 4; ++jj) acc[i][jj] += av[i] * bv[jj];
    }
  }
#pragma unroll
  for (int i = 0; i < 4; ++i) {
    int mm = m0 + ty * 4 + i;
    size_t ci = (size_t)mm * D_ + (n0 + tx * 4);
    ushort4 hv, lv;
    unsigned int s0 = split2(acc[i][0]), s1 = split2(acc[i][1]);
    unsigned int s2 = split2(acc[i][2]), s3 = split2(acc[i][3]);
    hv.x = (u16)s0; hv.y = (u16)s1; hv.z = (u16)s2; hv.w = (u16)s3;
    lv.x = (u16)(s0 >> 16); lv.y = (u16)(s1 >> 16); lv.z = (u16)(s2 >> 16); lv.w = (u16)(s3 >> 16);
    *(ushort4*)&Ch[ci] = hv;
    *(ushort4*)&Ch[ci + NBLD_] = lv;
  }
}

// ------- weighted delay-gather: fp32 V -> fp16 single plane (all layers) -------
__global__ __launch_bounds__(256) void gather_k(const float* __restrict__ v,
    const float* __restrict__ tc, const int* __restrict__ dly, u16* __restrict__ out,
    int lowp)
{
  int tid = blockIdx.x * 256 + threadIdx.x;
  int c4 = tid & 127;
  int row = tid >> 7;
  int b = row >> 10, l = row & (L_ - 1);
  const float4* vb = (const float4*)(v + (size_t)b * L_ * D_);
  float4 o = make_float4(0.f, 0.f, 0.f, 0.f);
#pragma unroll
  for (int k = 0; k < TOPK_; ++k) {
    int ld = (l + dly[b * TOPK_ + k]) & (L_ - 1);
    float w = tc[b * TOPK_ + k];
    float4 vv = vb[(size_t)ld * (D_ / 4) + c4];
    o.x += w * vv.x; o.y += w * vv.y; o.z += w * vv.z; o.w += w * vv.w;
  }
  if (lowp) {
    ushort4 hv;
    hv.x = f2h(o.x); hv.y = f2h(o.y); hv.z = f2h(o.z); hv.w = f2h(o.w);
    *(ushort4*)&out[(size_t)tid * 4] = hv;
  } else {
    unsigned int s0 = split2(o.x), s1 = split2(o.y), s2 = split2(o.z), s3 = split2(o.w);
    ushort4 hv, lv;
    hv.x = (u16)s0; hv.y = (u16)s1; hv.z = (u16)s2; hv.w = (u16)s3;
    lv.x = (u16)(s0 >> 16); lv.y = (u16)(s1 >> 16); lv.z = (u16)(s2 >> 16); lv.w = (u16)(s3 >> 16);
    *(ushort4*)&out[(size_t)tid * 4] = hv;
    *(ushort4*)&out[(size_t)tid * 4 + NBLD_] = lv;
  }
}

// ------- series decomposition: fp32 in -> split bf16 h planes (+optional fp16 copy) -------
// Sliding-window 25-tap moving average (2 LDS reads/row, wave owns 32 rows).
__global__ __launch_bounds__(256) void decomp_k(const float* __restrict__ s,
                                                u16* __restrict__ outh,
                                                u16* __restrict__ outf)
{
  __shared__ float tile[152][64];
  const int t = threadIdx.x;
  const int l0 = blockIdx.x * 128, d0 = blockIdx.y * 64, b = blockIdx.z;
  const float* sb = s + (size_t)b * L_ * D_;
  for (int idx = t; idx < 152 * 16; idx += 256) {
    int row = idx >> 4, c4 = (idx & 15) * 4;
    int lsrc = l0 - 12 + row;
    lsrc = lsrc < 0 ? 0 : (lsrc > L_ - 1 ? L_ - 1 : lsrc);
    *(float4*)&tile[row][c4] = *(const float4*)&sb[(size_t)lsrc * D_ + d0 + c4];
  }
  __syncthreads();
  const int d = t & 63, lb = (t >> 6) * 32;
  float sum = 0.f;
#pragma unroll
  for (int j = 0; j < 25; ++j) sum += tile[lb + j][d];
  for (int it = 0; it < 32; ++it) {
    int lp = lb + it;
    float val = tile[lp + 12][d] - sum * (1.0f / 25.0f);
    unsigned int sp = split2(val);
    size_t ci = ((size_t)b * L_ + l0 + lp) * D_ + d0 + d;
    outh[ci] = (u16)(sp & 0xffffu);
    outh[ci + NBLD_] = (u16)(sp >> 16);
    if (outf) outf[ci] = f2h(val);
    if (it < 31) sum += tile[lp + 25][d] - tile[lp][d];
  }
}

// ---------------- LayerNorm over D: one wave per row, shuffle reduce ----------------
__global__ __launch_bounds__(256) void ln_k(const u16* __restrict__ ah,
    const float* __restrict__ g, const float* __restrict__ be, float* __restrict__ out)
{
  const int row = blockIdx.x * 4 + (threadIdx.x >> 6);
  const int lane = threadIdx.x & 63;
  const size_t base = (size_t)row * D_;
  uint4 hv = *(const uint4*)&ah[base + lane * 8];
  uint4 lv = *(const uint4*)&ah[base + lane * 8 + NBLD_];
  const unsigned int* hp = (const unsigned int*)&hv;
  const unsigned int* lp = (const unsigned int*)&lv;
  float x[8];
  float s = 0.f;
#pragma unroll
  for (int j = 0; j < 4; ++j) {
    float a0 = bf2f((u16)(hp[j] & 0xffffu)) + bf2f((u16)(lp[j] & 0xffffu));
    float a1 = bf2f((u16)(hp[j] >> 16)) + bf2f((u16)(lp[j] >> 16));
    x[2 * j] = a0; x[2 * j + 1] = a1; s += a0 + a1;
  }
#pragma unroll
  for (int o = 32; o > 0; o >>= 1) s += __shfl_xor(s, o);
  float mu = s * (1.0f / 512.0f);
  float v = 0.f;
#pragma unroll
  for (int j = 0; j < 8; ++j) { x[j] -= mu; v += x[j] * x[j]; }
#pragma unroll
  for (int o = 32; o > 0; o >>= 1) v += __shfl_xor(v, o);
  float rs = rsqrtf(v * (1.0f / 512.0f) + 1e-5f);
  float4 g0 = *(const float4*)&g[lane * 8];
  float4 g1 = *(const float4*)&g[lane * 8 + 4];
  float4 b0 = *(const float4*)&be[lane * 8];
  float4 b1 = *(const float4*)&be[lane * 8 + 4];
  float4 o0 = make_float4(x[0] * rs * g0.x + b0.x, x[1] * rs * g0.y + b0.y,
                          x[2] * rs * g0.z + b0.z, x[3] * rs * g0.w + b0.w);
  float4 o1 = make_float4(x[4] * rs * g1.x + b1.x, x[5] * rs * g1.y + b1.y,
                          x[6] * rs * g1.z + b1.z, x[7] * rs * g1.w + b1.w);
  *(float4*)&out[base + lane * 8] = o0;
  *(float4*)&out[base + lane * 8 + 4] = o1;
}

// ---------------- per-(b,d) time mean over L (256 blocks, no 2nd pass) ----------------
__global__ __launch_bounds__(256) void colmean_mu_k(const float* __restrict__ a,
                                                    float* __restrict__ mu)
{
  __shared__ float red[256];
  const int b = blockIdx.x, d0 = blockIdx.y * 64;
  const int d = threadIdx.x & 63, lg = threadIdx.x >> 6;
  const float* p = a + (size_t)b * L_ * D_ + d0 + d;
  float sum = 0.f;
  for (int l = lg; l < L_; l += 4) sum += p[(size_t)l * D_];
  red[threadIdx.x] = sum;
  __syncthreads();
  if (lg == 0) {
    float s = red[d] + red[d + 64] + red[d + 128] + red[d + 192];
    mu[(b << 9) + d0 + d] = s * (1.0f / 1024.0f);
  }
}

extern "C" void kernel_launch(void* const* d_in, const int* in_sizes, int n_in,
                              void* d_out, int out_size, void* d_ws, size_t ws_size,
                              hipStream_t stream) {
  (void)n_in; (void)in_sizes; (void)ws_size; (void)out_size;
  const float* x    = (const float*)d_in[0];
  const float* embw = (const float*)d_in[1];
  const float* wq   = (const float*)d_in[2];
  const float* bq   = (const float*)d_in[3];
  const float* wk   = (const float*)d_in[4];
  const float* bk   = (const float*)d_in[5];
  const float* wv   = (const float*)d_in[6];
  const float* bv   = (const float*)d_in[7];
  const float* wo   = (const float*)d_in[8];
  const float* bo   = (const float*)d_in[9];
  const float* w1   = (const float*)d_in[10];
  const float* w2   = (const float*)d_in[11];
  const float* lng  = (const float*)d_in[12];
  const float* lnb  = (const float*)d_in[13];
  const float* pw   = (const float*)d_in[14];
  const float* pb   = (const float*)d_in[15];

  const size_t nBLD = NBLD_;
  u16*   hh  = (u16*)d_ws;                       // h bf16 hi ; lo at +nBLD
  float* t0f = (float*)(hh + 2 * nBLD);
  float* t1f = t0f + nBLD;
  u16*   t1h = (u16*)t1f;
  float* Sre = t1f + nBLD;                       // spectrum accumulators (B x 1024)
  float* Sim = Sre + (size_t)B_ * L_;
  float* tc    = Sim + (size_t)B_ * L_;
  int*   dly   = (int*)(tc + B_ * TOPK_);
  u16* base = (u16*)(dly + B_ * TOPK_ + 64);
  const size_t nDD = (size_t)NL_ * D_ * D_, nDF = (size_t)NL_ * D_ * DFF_;
  u16* wqTh = base;             u16* wqTl = wqTh + nDD;
  u16* wkTh = wqTl + nDD;       u16* wkTl = wkTh + nDD;
  u16* wvTh = wkTl + nDD;       u16* wvTl = wvTh + nDD;
  u16* woTh = wvTl + nDD;       u16* woTl = woTh + nDD;
  u16* w1Th = woTl + nDD;       u16* w1Tl = w1Th + nDF;
  u16* w2Th = w1Tl + nDF;       u16* w2Tl = w2Th + nDF;
  // NOTE: wo / w1 / w2 hold fp16 content in their hi-plane slots for ALL
  // layers (transp_split_k f16_from=0); lo slots unused.  The fp16 h copy
  // for FFN W1 lives in t1's lo half (dead once gather/u went fp16-single).
  // Workspace layout/size identical to the verified R8/R10/R11 kernels.
  u16* h16 = t1h + nBLD;

  dim3 blk(256);
  const dim3 gGemm(512, 8);
  const dim3 gMfma(256, 4);
  const dim3 gMfma2(256, 4, 2);    // merged Q/K
  const dim3 gFft(64, B_);

  // batched weight transposes: z = layer; wo/w1/w2 all layers fp16 planes
  transp_split_k<<<dim3(16, 16, 3), blk, 0, stream>>>(wq, wqTh, wqTl, D_, D_, D_ * D_, 3);
  transp_split_k<<<dim3(16, 16, 3), blk, 0, stream>>>(wk, wkTh, wkTl, D_, D_, D_ * D_, 3);
  transp_split_k<<<dim3(16, 16, 3), blk, 0, stream>>>(wv, wvTh, wvTl, D_, D_, D_ * D_, 3);
  transp_split_k<<<dim3(16, 16, 3), blk, 0, stream>>>(wo, woTh, woTl, D_, D_, D_ * D_, 0);
  transp_split_k<<<dim3(16, 64, 3), blk, 0, stream>>>(w1, w1Th, w1Tl, D_, DFF_, D_ * DFF_, 0);
  transp_split_k<<<dim3(64, 16, 3), blk, 0, stream>>>(w2, w2Th, w2Tl, DFF_, D_, DFF_ * D_, 0);

  embed_k<<<gGemm, blk, 0, stream>>>(x, embw, hh);
  zero_k<<<dim3(256), blk, 0, stream>>>(Sre, 2 * B_ * L_);

  for (int l = 0; l < NL_; ++l) {
    // Q/K: split-bf16 everywhere (corr top-6 is a discrete selection;
    // fp16-level noise in h is proven selection-safe by R10/R11's
    // bit-identical absmax, so O/W1/W2 run fp16 on ALL layers).
    // V (reads bf16 h planes): layers 0,1 split; layer 2 plain bf16-hi.
    const bool last = (l == NL_ - 1);
    const size_t oDD = (size_t)l * D_ * D_;
    const u16* hl = hh + nBLD;

    // merged Q (z=0) and K (z=1) projections -> fp32 (mode 0, no residual)
    mfma_split_gemm_k<<<gMfma2, blk, 0, stream>>>(hh, hl, D_, wqTh + oDD, wqTl + oDD, D_,
        t0f, D_, bq + (size_t)l * D_, nullptr, nullptr, D_, 0,
        wkTh + oDD, wkTl + oDD, t1f, bk + (size_t)l * D_);

    // FFT autocorrelation: forward+pack+accumulate, then iFFT fused with top-k
    fftcorr_k<<<gFft, blk, 0, stream>>>(t0f, t1f, Sre, Sim);
    ifft_topk_k<<<dim3(B_), blk, 0, stream>>>(Sre, Sim, tc, dly);

    // V -> t0f (fp32); gather -> t1-hi (fp16 single)
    if (last)
      mfma_plain_gemm_k<<<gMfma, blk, 0, stream>>>(hh, D_, wvTh + oDD, D_,
          t0f, D_, bv + (size_t)l * D_, nullptr, nullptr, D_, 0);
    else
      mfma_split_gemm_k<<<gMfma, blk, 0, stream>>>(hh, hl, D_, wvTh + oDD, wvTl + oDD, D_,
          t0f, D_, bv + (size_t)l * D_, nullptr, nullptr, D_, 0,
          nullptr, nullptr, nullptr, nullptr);
    gather_k<<<dim3(16384), blk, 0, stream>>>(t0f, tc, dly, t1h, 1);

    // out proj (fp16) + bias + residual(h) -> t0f ; decomp -> h planes + h16
    mfma_f16_gemm_k<<<gMfma, blk, 0, stream>>>(t1h, D_, woTh + oDD, D_,
        t0f, D_, bo + (size_t)l * D_, hh, hl, D_, 0);
    decomp_k<<<dim3(8, 8, B_), blk, 0, stream>>>(t0f, hh, h16);

    // FFN (fp16): 2 M-chunks x 2 DFF-chunks.  u chunk (fp16) in t1-hi.
    for (int mc = 0; mc < 2; ++mc) {
      const size_t moff = (size_t)mc * 16384 * D_;
      for (int c = 0; c < 2; ++c) {
        const size_t o1 = (size_t)l * D_ * DFF_ + (size_t)c * 1024 * D_;
        const size_t o2 = (size_t)l * DFF_ * D_ + (size_t)c * 1024;
        mfma_f16_gemm_k<<<dim3(128, 8), blk, 0, stream>>>(h16 + moff, D_, w1Th + o1, D_,
            t1h, 1024, nullptr, nullptr, nullptr, D_, 4);
        if (c == 0)
          mfma_f16_gemm_k<<<dim3(128, 4), blk, 0, stream>>>(t1h, 1024, w2Th + o2, DFF_,
              t0f + moff, D_, nullptr, hh + moff, hl + moff, 1024, 0);
        else
          mfma_f16_gemm_k<<<dim3(128, 4), blk, 0, stream>>>(t1h, 1024, w2Th + o2, DFF_,
              t0f + moff, D_, nullptr, nullptr, nullptr, 1024, 2);
      }
    }
    decomp_k<<<dim3(8, 8, B_), blk, 0, stream>>>(t0f, hh, nullptr);
  }

  ln_k<<<dim3(B_ * L_ / 4), blk, 0, stream>>>(hh, lng, lnb, t0f);
  colmean_mu_k<<<dim3(B_, 8), blk, 0, stream>>>(t0f, t1f);     // mu (B x D) in t1f
  gemm_k<<<dim3(512, 1), blk, 0, stream>>>(t0f, D_, pw, CIN_, (float*)d_out, CIN_, pb, D_, t1f);
}

// Round 13
// 2437.018 us; speedup vs baseline: 1.2456x; 1.0644x over previous
//
#include <hip/hip_runtime.h>
#include <hip/hip_bf16.h>
#include <math.h>

#define B_   32
#define L_   1024
#define CIN_ 64
#define D_   512
#define DFF_ 2048
#define NL_  3
#define TOPK_ 6
#define NBLD_ ((size_t)B_ * L_ * D_)

#define TM 64
#define TN 64
#define TBK 16

typedef unsigned short u16;
typedef _Float16 f16x8 __attribute__((ext_vector_type(8)));
typedef float  f32x4  __attribute__((ext_vector_type(4)));

typedef const __attribute__((address_space(1))) void* gp1_t;
typedef __attribute__((address_space(3))) void* lp3_t;

__device__ __forceinline__ void gll16(const void* g, void* l) {
  __builtin_amdgcn_global_load_lds((gp1_t)g, (lp3_t)l, 16, 0, 0);
}

__device__ __forceinline__ float bf2f(u16 u) {
  return __uint_as_float(((unsigned int)u) << 16);
}
__device__ __forceinline__ u16 f2bf(float f) {
  unsigned int u = __float_as_uint(f);
  return (u16)((u + 0x7fffu + ((u >> 16) & 1u)) >> 16);   // RNE
}
__device__ __forceinline__ unsigned int split2(float f) {
  u16 hi = f2bf(f);
  u16 lo = f2bf(f - bf2f(hi));
  return (unsigned int)hi | ((unsigned int)lo << 16);
}
__device__ __forceinline__ u16 f2h(float f) {
  union { _Float16 h; u16 u; } cv;
  cv.h = (_Float16)f;                                      // v_cvt_f16_f32 RNE
  return cv.u;
}
__device__ __forceinline__ float h2f(u16 u) {
  union { u16 u; _Float16 h; } cv;
  cv.u = u;
  return (float)cv.h;
}
__device__ __forceinline__ float gelu_f(float x) {
  return 0.5f * x * (1.0f + erff(x * 0.70710678118654752440f));
}

__global__ __launch_bounds__(256) void zero_k(float* __restrict__ p, int n) {
  int i = blockIdx.x * 256 + threadIdx.x;
  if (i < n) p[i] = 0.f;
}

// ------- weight transpose (z = layer): fp16 single plane into the hi slot.
// (Split-bf16 branch retained for f16_from>z usage; currently all-fp16.)
__global__ __launch_bounds__(256) void transp_split_k(const float* __restrict__ W,
                                                      u16* __restrict__ WTh,
                                                      u16* __restrict__ WTl,
                                                      int K, int N, int stride,
                                                      int f16_from) {
  __shared__ float tile[32][33];
  const int z = blockIdx.z;
  W   += (size_t)z * stride;
  WTh += (size_t)z * stride;
  WTl += (size_t)z * stride;
  const int t = threadIdx.x;
  const int k0 = blockIdx.x * 32, n0 = blockIdx.y * 32;
  const int tx = t & 31, ty = t >> 5;
#pragma unroll
  for (int i = 0; i < 4; ++i) {
    int kk = ty + i * 8;
    tile[kk][tx] = W[(size_t)(k0 + kk) * N + n0 + tx];
  }
  __syncthreads();
#pragma unroll
  for (int i = 0; i < 4; ++i) {
    int nn = ty + i * 8;
    float v = tile[tx][nn];
    size_t o = (size_t)(n0 + nn) * K + k0 + tx;
    if (z >= f16_from) {
      WTh[o] = f2h(v);
    } else {
      unsigned int s = split2(v);
      WTh[o] = (u16)(s & 0xffffu);
      WTl[o] = (u16)(s >> 16);
    }
  }
}

// ============ async fp16 single-pass MFMA GEMM (all projections) ============
// A and W are fp16 planes.  mode 0: +bias +R(bf16 hi/lo) -> fp32 ;
// mode 2: fp32 += ; mode 4: gelu -> fp16 plane ; mode 5: +bias -> fp16 plane.
__global__ __launch_bounds__(256) void mfma_f16_gemm_k(
    const u16* __restrict__ Ah, int lda,
    const u16* __restrict__ Wh, int ldwt,
    void* __restrict__ Cv, int ldc,
    const float* __restrict__ bias,
    const u16* __restrict__ Rh, const u16* __restrict__ Rl,
    int K, int mode)
{
  __shared__ __align__(16) char smem[32768];
  u16* Ash = (u16*)smem;
  u16* Bsh = Ash + 128 * 32;
  const int t = threadIdx.x;
  const int m0 = blockIdx.x * 128, n0 = blockIdx.y * 128;
  const int lane = t & 63, w = t >> 6;
  const int lrow = lane >> 2, lq = lane & 3;
  const int qg8 = (lq ^ ((lrow >> 1) & 3)) * 8;
  const int wm = (w & 1) * 64, wn = (w >> 1) * 64;
  const int lm = lane & 15, quad = lane >> 4;
  const int kq8 = (quad ^ ((lm >> 1) & 3)) * 8;

  f32x4 acc[4][4];
#pragma unroll
  for (int i = 0; i < 4; ++i)
#pragma unroll
    for (int j = 0; j < 4; ++j) acc[i][j] = (f32x4){0.f, 0.f, 0.f, 0.f};

  for (int k0 = 0; k0 < K; k0 += 32) {
    __syncthreads();
#pragma unroll
    for (int seg = 0; seg < 2; ++seg) {
      const int r0 = w * 32 + seg * 16;
      const size_t ga = (size_t)(m0 + r0 + lrow) * lda + k0 + qg8;
      const size_t gb = (size_t)(n0 + r0 + lrow) * ldwt + k0 + qg8;
      gll16(Ah + ga, &Ash[r0 * 32]);
      gll16(Wh + gb, &Bsh[r0 * 32]);
    }
    __syncthreads();

    f16x8 af[4], bf[4];
#pragma unroll
    for (int mi = 0; mi < 4; ++mi)
      af[mi] = *(const f16x8*)&Ash[(wm + mi * 16 + lm) * 32 + kq8];
#pragma unroll
    for (int ni = 0; ni < 4; ++ni)
      bf[ni] = *(const f16x8*)&Bsh[(wn + ni * 16 + lm) * 32 + kq8];
#pragma unroll
    for (int mi = 0; mi < 4; ++mi)
#pragma unroll
      for (int ni = 0; ni < 4; ++ni)
        acc[mi][ni] = __builtin_amdgcn_mfma_f32_16x16x32_f16(af[mi], bf[ni], acc[mi][ni], 0, 0, 0);
  }

  float bcol[4];
#pragma unroll
  for (int ni = 0; ni < 4; ++ni)
    bcol[ni] = (bias && (mode == 0 || mode == 5)) ? bias[n0 + wn + ni * 16 + lm] : 0.f;
  __syncthreads();
  float* epi = (float*)smem + w * 2048;
  float* Cf = (float*)Cv;
  u16* Cu = (u16*)Cv;
#pragma unroll
  for (int mi2 = 0; mi2 < 2; ++mi2) {
#pragma unroll
    for (int mm = 0; mm < 2; ++mm) {
      int mi = mi2 * 2 + mm;
#pragma unroll
      for (int ni = 0; ni < 4; ++ni)
#pragma unroll
        for (int r = 0; r < 4; ++r)
          epi[(mm * 16 + quad * 4 + r) * 64 + ni * 16 + lm] = acc[mi][ni][r] + bcol[ni];
    }
#pragma unroll
    for (int i = 0; i < 8; ++i) {
      int f = lane + 64 * i;
      int row = f >> 4, c4 = f & 15;
      int gr = m0 + wm + mi2 * 32 + row;
      int gc = n0 + wn + c4 * 4;
      size_t ci = (size_t)gr * ldc + gc;
      float4 v = *(const float4*)&epi[row * 64 + c4 * 4];
      if (mode == 0) {
        if (Rh) {
          ushort4 rh = *(const ushort4*)&Rh[ci];
          ushort4 rl = *(const ushort4*)&Rl[ci];
          v.x += bf2f(rh.x) + bf2f(rl.x); v.y += bf2f(rh.y) + bf2f(rl.y);
          v.z += bf2f(rh.z) + bf2f(rl.z); v.w += bf2f(rh.w) + bf2f(rl.w);
        }
        *(float4*)&Cf[ci] = v;
      } else if (mode == 2) {
        float4 o = *(const float4*)&Cf[ci];
        v.x += o.x; v.y += o.y; v.z += o.z; v.w += o.w;
        *(float4*)&Cf[ci] = v;
      } else if (mode == 5) {         // +bias -> fp16 plane (Q/K projections)
        ushort4 hv;
        hv.x = f2h(v.x); hv.y = f2h(v.y); hv.z = f2h(v.z); hv.w = f2h(v.w);
        *(ushort4*)&Cu[ci] = hv;
      } else {                         // mode 4: gelu -> fp16 plane
        ushort4 hv;
        hv.x = f2h(gelu_f(v.x)); hv.y = f2h(gelu_f(v.y));
        hv.z = f2h(gelu_f(v.z)); hv.w = f2h(gelu_f(v.w));
        *(ushort4*)&Cu[ci] = hv;
      }
    }
  }
}

// ============ FFT-based autocorrelation (fp16 q/k inputs) ============
__global__ __launch_bounds__(256) void fftcorr_k(
    const u16* __restrict__ q, const u16* __restrict__ kv,
    float* __restrict__ Sre, float* __restrict__ Sim)
{
  __shared__ float zre[1024 * 9];
  __shared__ float zim[1024 * 9];
  __shared__ float twr[512];
  __shared__ float twi[512];
  const int t = threadIdx.x;
  const int b = blockIdx.y;
  const int d0 = blockIdx.x * 8;
  const int ch = t & 7, lidx = t >> 3;     // lidx in 0..31

  for (int k = t; k < 512; k += 256) {
    float ang = (float)k * 6.13592315154256e-3f;   // 2*pi/1024
    twr[k] = cosf(ang);
    twi[k] = -sinf(ang);
  }

  const size_t gbase = (((size_t)b << 10)) * D_ + d0 + ch;
  for (int it = 0; it < 32; ++it) {
    int l = (lidx << 5) + it;
    float qv = h2f(q[gbase + (size_t)l * D_]);
    float kw = h2f(kv[gbase + (size_t)l * D_]);
    int p = __brev((unsigned)l) >> 22;
    zre[p * 9 + ch] = qv;
    zim[p * 9 + ch] = kw;
  }
  __syncthreads();

  const int gg = t >> 3;                   // 0..31
#pragma unroll
  for (int s = 0; s < 10; s += 2) {
    const int m = 1 << s;
#pragma unroll
    for (int it2 = 0; it2 < 8; ++it2) {
      int g = gg + (it2 << 5);             // 0..255
      int wi_ = g & (m - 1);
      int base = ((g >> s) << (s + 2)) | wi_;
      int i0 = (base) * 9 + ch;
      int i1 = (base + m) * 9 + ch;
      int i2 = (base + 2 * m) * 9 + ch;
      int i3 = (base + 3 * m) * 9 + ch;
      int w1x = wi_ << (9 - s);
      int w2x = wi_ << (8 - s);
      int w2y = (wi_ + m) << (8 - s);
      float w1r = twr[w1x], w1i = twi[w1x];
      float w2ar = twr[w2x], w2ai = twi[w2x];
      float w2br = twr[w2y], w2bi = twi[w2y];
      float ar = zre[i0], ai = zim[i0];
      float br = zre[i1], bi = zim[i1];
      float cr = zre[i2], ci = zim[i2];
      float dr = zre[i3], di = zim[i3];
      float t1r = br * w1r - bi * w1i, t1i = br * w1i + bi * w1r;
      float u0r = ar + t1r, u0i = ai + t1i;
      float u1r = ar - t1r, u1i = ai - t1i;
      float t3r = dr * w1r - di * w1i, t3i = dr * w1i + di * w1r;
      float u2r = cr + t3r, u2i = ci + t3i;
      float u3r = cr - t3r, u3i = ci - t3i;
      float v0r = u2r * w2ar - u2i * w2ai, v0i = u2r * w2ai + u2i * w2ar;
      float v1r = u3r * w2br - u3i * w2bi, v1i = u3r * w2bi + u3i * w2br;
      zre[i0] = u0r + v0r; zim[i0] = u0i + v0i;
      zre[i2] = u0r - v0r; zim[i2] = u0i - v0i;
      zre[i1] = u1r + v1r; zim[i1] = u1i + v1i;
      zre[i3] = u1r - v1r; zim[i3] = u1i - v1i;
    }
    __syncthreads();
  }

  for (int it = 0; it <= 16; ++it) {
    int f = gg + (it << 5);
    if (f <= 512) {                        // uniform within each 8-lane octet
      int fm = (1024 - f) & 1023;
      float zr = zre[f * 9 + ch],  zi0 = zim[f * 9 + ch];
      float mr = zre[fm * 9 + ch], mi0 = zim[fm * 9 + ch];
      float Qr = 0.5f * (zr + mr),  Qi = 0.5f * (zi0 - mi0);
      float Kr = 0.5f * (zi0 + mi0), Ki = -0.5f * (zr - mr);
      float Pr = Qr * Kr + Qi * Ki;
      float Pi = Qi * Kr - Qr * Ki;
      Pr += __shfl_xor(Pr, 1); Pi += __shfl_xor(Pi, 1);
      Pr += __shfl_xor(Pr, 2); Pi += __shfl_xor(Pi, 2);
      Pr += __shfl_xor(Pr, 4); Pi += __shfl_xor(Pi, 4);
      if (ch == 0) {
        atomicAdd(&Sre[(b << 10) + f], Pr);
        atomicAdd(&Sim[(b << 10) + f], Pi);
      }
    }
  }
}

// ifft_topk_k: per-b inverse FFT + top-6 + softmax.  Self-cleans S.
__global__ __launch_bounds__(256) void ifft_topk_k(
    float* __restrict__ Sre, float* __restrict__ Sim,
    float* __restrict__ tc, int* __restrict__ dly)
{
  __shared__ float re[1024], im[1024];
  __shared__ float twr[512], twi[512];
  __shared__ float rv[256];
  __shared__ int ri[256];
  __shared__ float wsel[TOPK_];
  __shared__ int dsel[TOPK_];
  const int b = blockIdx.x, t = threadIdx.x;

  for (int k = t; k < 512; k += 256) {
    float ang = (float)k * 6.13592315154256e-3f;
    twr[k] = cosf(ang);
    twi[k] = sinf(ang);
  }
  for (int l = t; l < 1024; l += 256) {
    int f = (l <= 512) ? l : 1024 - l;
    float sr = Sre[(b << 10) + f];
    float si = Sim[(b << 10) + f];
    if (l > 512) si = -si;
    int p = __brev((unsigned)l) >> 22;
    re[p] = sr; im[p] = si;
  }
  __syncthreads();
  for (int f = t; f <= 512; f += 256) {
    Sre[(b << 10) + f] = 0.f;
    Sim[(b << 10) + f] = 0.f;
  }

#pragma unroll
  for (int s = 0; s < 10; s += 2) {
    const int m = 1 << s;
    int wi_ = t & (m - 1);
    int base = ((t >> s) << (s + 2)) | wi_;
    int i0 = base, i1 = base + m, i2 = base + 2 * m, i3 = base + 3 * m;
    int w1x = wi_ << (9 - s);
    int w2x = wi_ << (8 - s);
    int w2y = (wi_ + m) << (8 - s);
    float w1r = twr[w1x], w1i = twi[w1x];
    float w2ar = twr[w2x], w2ai = twi[w2x];
    float w2br = twr[w2y], w2bi = twi[w2y];
    float ar = re[i0], ai = im[i0];
    float br = re[i1], bi = im[i1];
    float cr = re[i2], ci = im[i2];
    float dr = re[i3], di = im[i3];
    float t1r = br * w1r - bi * w1i, t1i = br * w1i + bi * w1r;
    float u0r = ar + t1r, u0i = ai + t1i;
    float u1r = ar - t1r, u1i = ai - t1i;
    float t3r = dr * w1r - di * w1i, t3i = dr * w1i + di * w1r;
    float u2r = cr + t3r, u2i = ci + t3i;
    float u3r = cr - t3r, u3i = ci - t3i;
    float v0r = u2r * w2ar - u2i * w2ai, v0i = u2r * w2ai + u2i * w2ar;
    float v1r = u3r * w2br - u3i * w2bi, v1i = u3r * w2bi + u3i * w2br;
    re[i0] = u0r + v0r; im[i0] = u0i + v0i;
    re[i2] = u0r - v0r; im[i2] = u0i - v0i;
    re[i1] = u1r + v1r; im[i1] = u1i + v1i;
    re[i3] = u1r - v1r; im[i3] = u1i - v1i;
    __syncthreads();
  }

  const float scale = 1.0f / (1024.f * 512.f);
  for (int i = t; i < 1024; i += 256) re[i] *= scale;
  __syncthreads();

  for (int kk = 0; kk < TOPK_; ++kk) {
    float bv = -INFINITY; int bi = 0x7fffffff;
    for (int i = t; i < 1024; i += 256) {
      float v = re[i];
      if (v > bv) { bv = v; bi = i; }
    }
    rv[t] = bv; ri[t] = bi;
    __syncthreads();
    for (int s2 = 128; s2 > 0; s2 >>= 1) {
      if (t < s2) {
        if (rv[t + s2] > rv[t] || (rv[t + s2] == rv[t] && ri[t + s2] < ri[t])) {
          rv[t] = rv[t + s2]; ri[t] = ri[t + s2];
        }
      }
      __syncthreads();
    }
    if (t == 0) { wsel[kk] = rv[0]; dsel[kk] = ri[0]; re[ri[0]] = -INFINITY; }
    __syncthreads();
  }
  if (t == 0) {
    float m = wsel[0];
    float e[TOPK_], se = 0.f;
    for (int k = 0; k < TOPK_; ++k) { e[k] = expf(wsel[k] - m); se += e[k]; }
    for (int k = 0; k < TOPK_; ++k) {
      tc[b * TOPK_ + k] = e[k] / se;
      dly[b * TOPK_ + k] = dsel[k];
    }
  }
}

// ---------------- fp32 GEMM (final projection, fused col-mean subtract on A) ----------------
__global__ __launch_bounds__(256) void gemm_k(
    const float* __restrict__ A, int lda,
    const float* __restrict__ W, int ldw,
    float* __restrict__ C, int ldc,
    const float* __restrict__ bias,
    int K, const float* __restrict__ mu)
{
  __shared__ float As[TBK][TM + 4];
  __shared__ float Bs[TBK][TN + 4];
  const int t = threadIdx.x;
  const int m0 = blockIdx.x * TM;
  const int n0 = blockIdx.y * TN;
  const int tx = t & 15, ty = t >> 4;
  const int ar = t >> 2, akv = (t & 3) * 4;
  const int bkk = t >> 4, bc = (t & 15) * 4;
  const int mb = (m0 + ar) >> 10;          // batch of this A row
  float acc[4][4] = {};
  for (int k0 = 0; k0 < K; k0 += TBK) {
    float4 a4 = *(const float4*)&A[(size_t)(m0 + ar) * lda + (k0 + akv)];
    float4 w4 = *(const float4*)&W[(size_t)(k0 + bkk) * ldw + (n0 + bc)];
    if (mu) {
      float4 m4 = *(const float4*)&mu[(mb << 9) + k0 + akv];
      a4.x -= m4.x; a4.y -= m4.y; a4.z -= m4.z; a4.w -= m4.w;
    }
    __syncthreads();
    As[akv + 0][ar] = a4.x; As[akv + 1][ar] = a4.y;
    As[akv + 2][ar] = a4.z; As[akv + 3][ar] = a4.w;
    *(float4*)&Bs[bkk][bc] = w4;
    __syncthreads();
#pragma unroll
    for (int kk = 0; kk < TBK; ++kk) {
      float4 a = *(const float4*)&As[kk][ty * 4];
      float4 b = *(const float4*)&Bs[kk][tx * 4];
      float av[4] = {a.x, a.y, a.z, a.w};
      float bv[4] = {b.x, b.y, b.z, b.w};
#pragma unroll
      for (int i = 0; i < 4; ++i)
#pragma unroll
        for (int j = 0; j < 4; ++j) acc[i][j] += av[i] * bv[j];
    }
  }
#pragma unroll
  for (int i = 0; i < 4; ++i) {
    int m = m0 + ty * 4 + i;
    float* crow = &C[(size_t)m * ldc + (n0 + tx * 4)];
    float4 v = make_float4(acc[i][0], acc[i][1], acc[i][2], acc[i][3]);
    if (bias) {
      const float* bp = &bias[n0 + tx * 4];
      v.x += bp[0]; v.y += bp[1]; v.z += bp[2]; v.w += bp[3];
    }
    *(float4*)crow = v;
  }
}

// ------- embedding: circular conv1d(k=3); split bf16 h planes + fp16 h plane -------
__global__ __launch_bounds__(256) void embed_k(
    const float* __restrict__ x, const float* __restrict__ W,
    u16* __restrict__ Ch, u16* __restrict__ Cf)
{
  __shared__ float As[TBK][TM + 4];
  __shared__ float Bs[TBK][TN + 4];
  const int t = threadIdx.x;
  const int m0 = blockIdx.x * TM, n0 = blockIdx.y * TN;
  const int tx = t & 15, ty = t >> 4;
  const int ar = t >> 2, akv = (t & 3) * 4;
  const int bkk = t >> 4, bc = (t & 15) * 4;
  const int m = m0 + ar, mb = m >> 10, ml = m & (L_ - 1);
  float acc[4][4] = {};
  for (int k0 = 0; k0 < 3 * CIN_; k0 += TBK) {
    int kcol = k0 + akv;
    int j = kcol >> 6, c = kcol & 63;
    int lsrc = (ml + j - 1 + L_) & (L_ - 1);
    float4 a4 = *(const float4*)&x[((size_t)mb * L_ + lsrc) * CIN_ + c];
    float4 w4 = *(const float4*)&W[(size_t)(k0 + bkk) * D_ + (n0 + bc)];
    __syncthreads();
    As[akv + 0][ar] = a4.x; As[akv + 1][ar] = a4.y;
    As[akv + 2][ar] = a4.z; As[akv + 3][ar] = a4.w;
    *(float4*)&Bs[bkk][bc] = w4;
    __syncthreads();
#pragma unroll
    for (int kk = 0; kk < TBK; ++kk) {
      float4 a = *(const float4*)&As[kk][ty * 4];
      float4 b = *(const float4*)&Bs[kk][tx * 4];
      float av[4] = {a.x, a.y, a.z, a.w};
      float bv[4] = {b.x, b.y, b.z, b.w};
#pragma unroll
      for (int i = 0; i < 4; ++i)
#pragma unroll
        for (int jj = 0; jj < 4; ++jj) acc[i][jj] += av[i] * bv[jj];
    }
  }
#pragma unroll
  for (int i = 0; i < 4; ++i) {
    int mm = m0 + ty * 4 + i;
    size_t ci = (size_t)mm * D_ + (n0 + tx * 4);
    ushort4 hv, lv, fv;
    unsigned int s0 = split2(acc[i][0]), s1 = split2(acc[i][1]);
    unsigned int s2 = split2(acc[i][2]), s3 = split2(acc[i][3]);
    hv.x = (u16)s0; hv.y = (u16)s1; hv.z = (u16)s2; hv.w = (u16)s3;
    lv.x = (u16)(s0 >> 16); lv.y = (u16)(s1 >> 16); lv.z = (u16)(s2 >> 16); lv.w = (u16)(s3 >> 16);
    fv.x = f2h(acc[i][0]); fv.y = f2h(acc[i][1]);
    fv.z = f2h(acc[i][2]); fv.w = f2h(acc[i][3]);
    *(ushort4*)&Ch[ci] = hv;
    *(ushort4*)&Ch[ci + NBLD_] = lv;
    *(ushort4*)&Cf[ci] = fv;
  }
}

// ------- weighted delay-gather: fp32 V -> fp16 single plane -------
__global__ __launch_bounds__(256) void gather_k(const float* __restrict__ v,
    const float* __restrict__ tc, const int* __restrict__ dly, u16* __restrict__ out)
{
  int tid = blockIdx.x * 256 + threadIdx.x;
  int c4 = tid & 127;
  int row = tid >> 7;
  int b = row >> 10, l = row & (L_ - 1);
  const float4* vb = (const float4*)(v + (size_t)b * L_ * D_);
  float4 o = make_float4(0.f, 0.f, 0.f, 0.f);
#pragma unroll
  for (int k = 0; k < TOPK_; ++k) {
    int ld = (l + dly[b * TOPK_ + k]) & (L_ - 1);
    float w = tc[b * TOPK_ + k];
    float4 vv = vb[(size_t)ld * (D_ / 4) + c4];
    o.x += w * vv.x; o.y += w * vv.y; o.z += w * vv.z; o.w += w * vv.w;
  }
  ushort4 hv;
  hv.x = f2h(o.x); hv.y = f2h(o.y); hv.z = f2h(o.z); hv.w = f2h(o.w);
  *(ushort4*)&out[(size_t)tid * 4] = hv;
}

// ------- series decomposition: fp32 in -> split bf16 h planes + fp16 h plane -------
// Sliding-window 25-tap moving average (2 LDS reads/row, wave owns 32 rows).
__global__ __launch_bounds__(256) void decomp_k(const float* __restrict__ s,
                                                u16* __restrict__ outh,
                                                u16* __restrict__ outf)
{
  __shared__ float tile[152][64];
  const int t = threadIdx.x;
  const int l0 = blockIdx.x * 128, d0 = blockIdx.y * 64, b = blockIdx.z;
  const float* sb = s + (size_t)b * L_ * D_;
  for (int idx = t; idx < 152 * 16; idx += 256) {
    int row = idx >> 4, c4 = (idx & 15) * 4;
    int lsrc = l0 - 12 + row;
    lsrc = lsrc < 0 ? 0 : (lsrc > L_ - 1 ? L_ - 1 : lsrc);
    *(float4*)&tile[row][c4] = *(const float4*)&sb[(size_t)lsrc * D_ + d0 + c4];
  }
  __syncthreads();
  const int d = t & 63, lb = (t >> 6) * 32;
  float sum = 0.f;
#pragma unroll
  for (int j = 0; j < 25; ++j) sum += tile[lb + j][d];
  for (int it = 0; it < 32; ++it) {
    int lp = lb + it;
    float val = tile[lp + 12][d] - sum * (1.0f / 25.0f);
    unsigned int sp = split2(val);
    size_t ci = ((size_t)b * L_ + l0 + lp) * D_ + d0 + d;
    outh[ci] = (u16)(sp & 0xffffu);
    outh[ci + NBLD_] = (u16)(sp >> 16);
    outf[ci] = f2h(val);
    if (it < 31) sum += tile[lp + 25][d] - tile[lp][d];
  }
}

// ---------------- LayerNorm over D: one wave per row, shuffle reduce ----------------
__global__ __launch_bounds__(256) void ln_k(const u16* __restrict__ ah,
    const float* __restrict__ g, const float* __restrict__ be, float* __restrict__ out)
{
  const int row = blockIdx.x * 4 + (threadIdx.x >> 6);
  const int lane = threadIdx.x & 63;
  const size_t base = (size_t)row * D_;
  uint4 hv = *(const uint4*)&ah[base + lane * 8];
  uint4 lv = *(const uint4*)&ah[base + lane * 8 + NBLD_];
  const unsigned int* hp = (const unsigned int*)&hv;
  const unsigned int* lp = (const unsigned int*)&lv;
  float x[8];
  float s = 0.f;
#pragma unroll
  for (int j = 0; j < 4; ++j) {
    float a0 = bf2f((u16)(hp[j] & 0xffffu)) + bf2f((u16)(lp[j] & 0xffffu));
    float a1 = bf2f((u16)(hp[j] >> 16)) + bf2f((u16)(lp[j] >> 16));
    x[2 * j] = a0; x[2 * j + 1] = a1; s += a0 + a1;
  }
#pragma unroll
  for (int o = 32; o > 0; o >>= 1) s += __shfl_xor(s, o);
  float mu = s * (1.0f / 512.0f);
  float v = 0.f;
#pragma unroll
  for (int j = 0; j < 8; ++j) { x[j] -= mu; v += x[j] * x[j]; }
#pragma unroll
  for (int o = 32; o > 0; o >>= 1) v += __shfl_xor(v, o);
  float rs = rsqrtf(v * (1.0f / 512.0f) + 1e-5f);
  float4 g0 = *(const float4*)&g[lane * 8];
  float4 g1 = *(const float4*)&g[lane * 8 + 4];
  float4 b0 = *(const float4*)&be[lane * 8];
  float4 b1 = *(const float4*)&be[lane * 8 + 4];
  float4 o0 = make_float4(x[0] * rs * g0.x + b0.x, x[1] * rs * g0.y + b0.y,
                          x[2] * rs * g0.z + b0.z, x[3] * rs * g0.w + b0.w);
  float4 o1 = make_float4(x[4] * rs * g1.x + b1.x, x[5] * rs * g1.y + b1.y,
                          x[6] * rs * g1.z + b1.z, x[7] * rs * g1.w + b1.w);
  *(float4*)&out[base + lane * 8] = o0;
  *(float4*)&out[base + lane * 8 + 4] = o1;
}

// ---------------- per-(b,d) time mean over L (256 blocks, no 2nd pass) ----------------
__global__ __launch_bounds__(256) void colmean_mu_k(const float* __restrict__ a,
                                                    float* __restrict__ mu)
{
  __shared__ float red[256];
  const int b = blockIdx.x, d0 = blockIdx.y * 64;
  const int d = threadIdx.x & 63, lg = threadIdx.x >> 6;
  const float* p = a + (size_t)b * L_ * D_ + d0 + d;
  float sum = 0.f;
  for (int l = lg; l < L_; l += 4) sum += p[(size_t)l * D_];
  red[threadIdx.x] = sum;
  __syncthreads();
  if (lg == 0) {
    float s = red[d] + red[d + 64] + red[d + 128] + red[d + 192];
    mu[(b << 9) + d0 + d] = s * (1.0f / 1024.0f);
  }
}

extern "C" void kernel_launch(void* const* d_in, const int* in_sizes, int n_in,
                              void* d_out, int out_size, void* d_ws, size_t ws_size,
                              hipStream_t stream) {
  (void)n_in; (void)in_sizes; (void)ws_size; (void)out_size;
  const float* x    = (const float*)d_in[0];
  const float* embw = (const float*)d_in[1];
  const float* wq   = (const float*)d_in[2];
  const float* bq   = (const float*)d_in[3];
  const float* wk   = (const float*)d_in[4];
  const float* bk   = (const float*)d_in[5];
  const float* wv   = (const float*)d_in[6];
  const float* bv   = (const float*)d_in[7];
  const float* wo   = (const float*)d_in[8];
  const float* bo   = (const float*)d_in[9];
  const float* w1   = (const float*)d_in[10];
  const float* w2   = (const float*)d_in[11];
  const float* lng  = (const float*)d_in[12];
  const float* lnb  = (const float*)d_in[13];
  const float* pw   = (const float*)d_in[14];
  const float* pb   = (const float*)d_in[15];

  const size_t nBLD = NBLD_;
  u16*   hh  = (u16*)d_ws;                       // h bf16 hi ; lo at +nBLD (residual/LN)
  float* t0f = (float*)(hh + 2 * nBLD);
  u16*   t0h = (u16*)t0f;                        // Q fp16 plane ; K plane at +nBLD
  float* t1f = t0f + nBLD;
  u16*   t1h = (u16*)t1f;                        // gather/u fp16 plane (t1-hi)
  float* Sre = t1f + nBLD;                       // spectrum accumulators (B x 1024)
  float* Sim = Sre + (size_t)B_ * L_;
  float* tc    = Sim + (size_t)B_ * L_;
  int*   dly   = (int*)(tc + B_ * TOPK_);
  u16* base = (u16*)(dly + B_ * TOPK_ + 64);
  const size_t nDD = (size_t)NL_ * D_ * D_, nDF = (size_t)NL_ * D_ * DFF_;
  u16* wqTh = base;             u16* wqTl = wqTh + nDD;
  u16* wkTh = wqTl + nDD;       u16* wkTl = wkTh + nDD;
  u16* wvTh = wkTl + nDD;       u16* wvTl = wvTh + nDD;
  u16* woTh = wvTl + nDD;       u16* woTl = woTh + nDD;
  u16* w1Th = woTl + nDD;       u16* w1Tl = w1Th + nDF;
  u16* w2Th = w1Tl + nDF;       u16* w2Tl = w2Th + nDF;
  // ALL weights hold fp16 content in hi-plane slots (f16_from=0); lo unused.
  // h16 (fp16 h copy, GEMM A-input) lives in t1's lo half: it survives the
  // whole layer because Q/K outputs now pack into t0's two u16 planes
  // (t1 untouched until gather, which writes only t1-hi).
  // Workspace layout/size identical to the verified R8..R12 kernels.
  u16* h16 = t1h + nBLD;
  u16* qh  = t0h;
  u16* kh  = t0h + nBLD;

  dim3 blk(256);
  const dim3 gGemm(512, 8);
  const dim3 gMfma(256, 4);
  const dim3 gFft(64, B_);

  // batched weight transposes: z = layer; ALL fp16 planes
  transp_split_k<<<dim3(16, 16, 3), blk, 0, stream>>>(wq, wqTh, wqTl, D_, D_, D_ * D_, 0);
  transp_split_k<<<dim3(16, 16, 3), blk, 0, stream>>>(wk, wkTh, wkTl, D_, D_, D_ * D_, 0);
  transp_split_k<<<dim3(16, 16, 3), blk, 0, stream>>>(wv, wvTh, wvTl, D_, D_, D_ * D_, 0);
  transp_split_k<<<dim3(16, 16, 3), blk, 0, stream>>>(wo, woTh, woTl, D_, D_, D_ * D_, 0);
  transp_split_k<<<dim3(16, 64, 3), blk, 0, stream>>>(w1, w1Th, w1Tl, D_, DFF_, D_ * DFF_, 0);
  transp_split_k<<<dim3(64, 16, 3), blk, 0, stream>>>(w2, w2Th, w2Tl, DFF_, D_, DFF_ * D_, 0);

  embed_k<<<gGemm, blk, 0, stream>>>(x, embw, hh, h16);
  zero_k<<<dim3(256), blk, 0, stream>>>(Sre, 2 * B_ * L_);

  for (int l = 0; l < NL_; ++l) {
    // All projections single-pass fp16 (selection robustness at fp16 noise
    // level proven by R10-R12's bit-identical absmax).  h keeps bf16x2
    // planes for the residual adds and the final LayerNorm.
    const size_t oDD = (size_t)l * D_ * D_;
    const u16* hl = hh + nBLD;

    // Q -> t0-hi, K -> t0-lo (fp16 planes, +bias)
    mfma_f16_gemm_k<<<gMfma, blk, 0, stream>>>(h16, D_, wqTh + oDD, D_,
        qh, D_, bq + (size_t)l * D_, nullptr, nullptr, D_, 5);
    mfma_f16_gemm_k<<<gMfma, blk, 0, stream>>>(h16, D_, wkTh + oDD, D_,
        kh, D_, bk + (size_t)l * D_, nullptr, nullptr, D_, 5);

    // FFT autocorrelation (fp16 q/k), then iFFT fused with top-k
    fftcorr_k<<<gFft, blk, 0, stream>>>(qh, kh, Sre, Sim);
    ifft_topk_k<<<dim3(B_), blk, 0, stream>>>(Sre, Sim, tc, dly);

    // V -> t0f (fp32, t0 planes consumed); gather -> t1-hi (fp16)
    mfma_f16_gemm_k<<<gMfma, blk, 0, stream>>>(h16, D_, wvTh + oDD, D_,
        t0f, D_, bv + (size_t)l * D_, nullptr, nullptr, D_, 0);
    gather_k<<<dim3(16384), blk, 0, stream>>>(t0f, tc, dly, t1h);

    // out proj (fp16) + bias + residual(h) -> t0f ; decomp -> h planes + h16
    mfma_f16_gemm_k<<<gMfma, blk, 0, stream>>>(t1h, D_, woTh + oDD, D_,
        t0f, D_, bo + (size_t)l * D_, hh, hl, D_, 0);
    decomp_k<<<dim3(8, 8, B_), blk, 0, stream>>>(t0f, hh, h16);

    // FFN (fp16): 2 M-chunks x 2 DFF-chunks.  u chunk (fp16) in t1-hi.
    for (int mc = 0; mc < 2; ++mc) {
      const size_t moff = (size_t)mc * 16384 * D_;
      for (int c = 0; c < 2; ++c) {
        const size_t o1 = (size_t)l * D_ * DFF_ + (size_t)c * 1024 * D_;
        const size_t o2 = (size_t)l * DFF_ * D_ + (size_t)c * 1024;
        mfma_f16_gemm_k<<<dim3(128, 8), blk, 0, stream>>>(h16 + moff, D_, w1Th + o1, D_,
            t1h, 1024, nullptr, nullptr, nullptr, D_, 4);
        if (c == 0)
          mfma_f16_gemm_k<<<dim3(128, 4), blk, 0, stream>>>(t1h, 1024, w2Th + o2, DFF_,
              t0f + moff, D_, nullptr, hh + moff, hl + moff, 1024, 0);
        else
          mfma_f16_gemm_k<<<dim3(128, 4), blk, 0, stream>>>(t1h, 1024, w2Th + o2, DFF_,
              t0f + moff, D_, nullptr, nullptr, nullptr, 1024, 2);
      }
    }
    decomp_k<<<dim3(8, 8, B_), blk, 0, stream>>>(t0f, hh, h16);
  }

  ln_k<<<dim3(B_ * L_ / 4), blk, 0, stream>>>(hh, lng, lnb, t0f);
  colmean_mu_k<<<dim3(B_, 8), blk, 0, stream>>>(t0f, t1f);     // mu (B x D) in t1f
  gemm_k<<<dim3(512, 1), blk, 0, stream>>>(t0f, D_, pw, CIN_, (float*)d_out, CIN_, pb, D_, t1f);
}